// Round 5
// baseline (375.381 us; speedup 1.0000x reference)
//
#include <hip/hip_runtime.h>
#include <math.h>

#define TPB 256

typedef float2 cf;
typedef __attribute__((ext_vector_type(8))) short bf16x8;
typedef __attribute__((ext_vector_type(4))) float f32x4;

__device__ __forceinline__ cf cmk(float x, float y){ cf r; r.x=x; r.y=y; return r; }
__device__ __forceinline__ cf cml(cf a, cf b){ return cmk(a.x*b.x - a.y*b.y, a.x*b.y + a.y*b.x); }
__device__ __forceinline__ cf cad(cf a, cf b){ return cmk(a.x+b.x, a.y+b.y); }
__device__ __forceinline__ cf csb(cf a, cf b){ return cmk(a.x-b.x, a.y-b.y); }
__device__ __forceinline__ cf cjg(cf a){ return cmk(a.x, -a.y); }
__device__ __forceinline__ cf crcp(cf d){ float r = 1.0f/(d.x*d.x + d.y*d.y); return cmk(d.x*r, -d.y*r); }
__device__ __forceinline__ cf cdv(cf n, cf d){ return cml(n, crcp(d)); }
__device__ __forceinline__ float geluf(float z){ return 0.5f*z*(1.0f + erff(z*0.70710678118654752f)); }

// exp(sign*i*pi*f) via native v_sin/v_cos (input in revolutions)
__device__ __forceinline__ cf twid(float f, float sign){
  float h = f * 0.5f;
  float s = __builtin_amdgcn_sinf(h);
  float c0 = __builtin_amdgcn_cosf(h);
  return cmk(c0, sign * s);
}

__device__ __forceinline__ cf shflx(cf v, int m){
  return cmk(__shfl_xor(v.x, m), __shfl_xor(v.y, m));
}

__device__ __forceinline__ void bfsplit(float v, ushort* h, ushort* l){
  unsigned u = __float_as_uint(v);
  unsigned hr = (u + 0x7FFFu + ((u >> 16) & 1u)) & 0xFFFF0000u;
  *h = (ushort)(hr >> 16);
  float lv = v - __uint_as_float(hr);
  unsigned u2 = __float_as_uint(lv);
  *l = (ushort)((u2 + 0x7FFFu + ((u2 >> 16) & 1u)) >> 16);
}

// radix-4 butterflies on a register quad (strides 0,s,2s,3s), w1 = W(j, 4s)
__device__ __forceinline__ void dif4q(cf& q0, cf& q1, cf& q2, cf& q3, cf w1, float sign){
  cf w2 = cml(w1, w1);
  cf a1 = cad(q0, q2);
  cf c1 = cml(csb(q0, q2), w1);
  cf b1 = cad(q1, q3);
  cf d1 = cml(csb(q1, q3), cmk(-sign*w1.y, sign*w1.x));
  q0 = cad(a1, b1);
  q1 = cml(csb(a1, b1), w2);
  q2 = cad(c1, d1);
  q3 = cml(csb(c1, d1), w2);
}
__device__ __forceinline__ void dit4q(cf& q0, cf& q1, cf& q2, cf& q3, cf w1, float sign){
  cf w2 = cml(w1, w1);
  cf t1 = cml(q1, w2);
  cf a1 = cad(q0, t1), b1 = csb(q0, t1);
  cf t2 = cml(q3, w2);
  cf c1 = cad(q2, t2), d1 = csb(q2, t2);
  cf v1 = cml(c1, w1);
  cf v2 = cml(d1, cmk(-sign*w1.y, sign*w1.x));
  q0 = cad(a1, v1);
  q2 = csb(a1, v1);
  q1 = cad(b1, v2);
  q3 = csb(b1, v2);
}

// ---------------- legacy LDS FFT templates (used by k_kf, N=4096) ----------------
template<int N, int SSTART>
__device__ void fft_dif_r4(cf* __restrict__ a, float sign){
  #pragma unroll
  for (int s = SSTART; s >= 1; s >>= 2){
    __syncthreads();
    #pragma unroll
    for (int g = 0; g < (N >> 2) / TPB; g++){
      int w = (int)threadIdx.x + g * TPB;
      int j = w & (s - 1);
      int base = ((w & ~(s - 1)) << 2) | j;
      cf A0 = a[base], B0 = a[base + s], C0 = a[base + 2*s], D0 = a[base + 3*s];
      cf w1 = twid((float)j / (float)(2 * s), sign);
      cf w2 = cml(w1, w1);
      cf a1 = cad(A0, C0);
      cf c1 = cml(csb(A0, C0), w1);
      cf b1 = cad(B0, D0);
      cf d1 = cml(csb(B0, D0), cmk(-sign * w1.y, sign * w1.x));
      a[base]         = cad(a1, b1);
      a[base + s]     = cml(csb(a1, b1), w2);
      a[base + 2*s]   = cad(c1, d1);
      a[base + 3*s]   = cml(csb(c1, d1), w2);
    }
  }
  if constexpr ((__builtin_ctz(N) & 1) == 1){
    __syncthreads();
    #pragma unroll
    for (int g = 0; g < (N >> 1) / TPB; g++){
      int w = (int)threadIdx.x + g * TPB;
      int i = w << 1;
      cf u = a[i], v = a[i + 1];
      a[i] = cad(u, v);
      a[i + 1] = csb(u, v);
    }
  }
  __syncthreads();
}

template<int N>
__device__ void fft_dit_r4(cf* __restrict__ a, float sign){
  if constexpr ((__builtin_ctz(N) & 1) == 1){
    __syncthreads();
    #pragma unroll
    for (int g = 0; g < (N >> 1) / TPB; g++){
      int w = (int)threadIdx.x + g * TPB;
      int i = w << 1;
      cf u = a[i], v = a[i + 1];
      a[i] = cad(u, v);
      a[i + 1] = csb(u, v);
    }
  }
  constexpr int S0 = ((__builtin_ctz(N) & 1) == 1) ? 2 : 1;
  #pragma unroll
  for (int s = S0; s <= (N >> 2); s <<= 2){
    __syncthreads();
    #pragma unroll
    for (int g = 0; g < (N >> 2) / TPB; g++){
      int w = (int)threadIdx.x + g * TPB;
      int j = w & (s - 1);
      int base = ((w & ~(s - 1)) << 2) | j;
      cf A0 = a[base], B0 = a[base + s], C0 = a[base + 2*s], D0 = a[base + 3*s];
      cf w1 = twid((float)j / (float)(2 * s), sign);
      cf w2 = cml(w1, w1);
      cf t1 = cml(B0, w2);
      cf a1 = cad(A0, t1), b1 = csb(A0, t1);
      cf t2 = cml(D0, w2);
      cf c1 = cad(C0, t2), d1 = csb(C0, t2);
      cf v1 = cml(c1, w1);
      cf v2 = cml(d1, cmk(-sign * w1.y, sign * w1.x));
      a[base]         = cad(a1, v1);
      a[base + 2*s]   = csb(a1, v1);
      a[base + s]     = cad(b1, v2);
      a[base + 3*s]   = csb(b1, v2);
    }
  }
  __syncthreads();
}

__device__ __forceinline__ int brev12(int x){ return (int)(__brev((unsigned)x) >> 20); }

// ---------------- register FFT4096: M0 (slot n = t+256r) <-> M1 (n = 256(t>>4)+16u+(t&15)) ----------------
// LDS idx(n) = n + 4*(n>>8); buffer 4160 cf (33,280 B)

__device__ __forceinline__ void dif4096_reg(cf (&v)[16], cf* __restrict__ c, int t, int lo){
  // stage A (bits 11..8)
  #pragma unroll
  for (int r0 = 0; r0 < 4; r0++){
    cf w1 = twid((float)(t + 256*r0) * (1.0f/2048.0f), -1.0f);
    dif4q(v[r0], v[r0+4], v[r0+8], v[r0+12], w1, -1.0f);
  }
  {
    cf w1 = twid((float)t * (1.0f/512.0f), -1.0f);
    #pragma unroll
    for (int g = 0; g < 16; g += 4)
      dif4q(v[g], v[g+1], v[g+2], v[g+3], w1, -1.0f);
  }
  // T1
  __syncthreads();
  #pragma unroll
  for (int r = 0; r < 16; r++) c[t + 260*r] = v[r];
  __syncthreads();
  int m1 = (t >> 4) * 260 + lo;
  #pragma unroll
  for (int u = 0; u < 16; u++) v[u] = c[m1 + 16*u];
  // stage B (bits 7..4)
  #pragma unroll
  for (int u0 = 0; u0 < 4; u0++){
    cf w1 = twid((float)(16*u0 + lo) * (1.0f/128.0f), -1.0f);
    dif4q(v[u0], v[u0+4], v[u0+8], v[u0+12], w1, -1.0f);
  }
  {
    cf w1 = twid((float)lo * (1.0f/32.0f), -1.0f);
    #pragma unroll
    for (int g = 0; g < 16; g += 4)
      dif4q(v[g], v[g+1], v[g+2], v[g+3], w1, -1.0f);
  }
  // stage C (bits 3..0 via shuffles)
  {
    bool h8 = (lo & 8) != 0;
    cf tw8 = twid((float)(lo & 7) * 0.125f, -1.0f);
    #pragma unroll
    for (int u = 0; u < 16; u++){
      cf o = shflx(v[u], 8);
      v[u] = h8 ? cml(csb(o, v[u]), tw8) : cad(v[u], o);
    }
    bool h4 = (lo & 4) != 0;
    cf tw4 = twid((float)(lo & 3) * 0.25f, -1.0f);
    #pragma unroll
    for (int u = 0; u < 16; u++){
      cf o = shflx(v[u], 4);
      v[u] = h4 ? cml(csb(o, v[u]), tw4) : cad(v[u], o);
    }
    bool h2 = (lo & 2) != 0;
    cf tw2 = twid((float)(lo & 1) * 0.5f, -1.0f);
    #pragma unroll
    for (int u = 0; u < 16; u++){
      cf o = shflx(v[u], 2);
      v[u] = h2 ? cml(csb(o, v[u]), tw2) : cad(v[u], o);
    }
    bool h1 = (lo & 1) != 0;
    #pragma unroll
    for (int u = 0; u < 16; u++){
      cf o = shflx(v[u], 1);
      v[u] = h1 ? csb(o, v[u]) : cad(v[u], o);
    }
  }
  // write M1 for pointwise
  #pragma unroll
  for (int u = 0; u < 16; u++) c[m1 + 16*u] = v[u];
  __syncthreads();
}

__device__ __forceinline__ void dit4096_reg(cf (&v)[16], cf* __restrict__ c, int t, int lo){
  int m1 = (t >> 4) * 260 + lo;
  #pragma unroll
  for (int u = 0; u < 16; u++) v[u] = c[m1 + 16*u];
  // stage C' (strides 1,2,4,8)
  {
    bool h1 = (lo & 1) != 0;
    #pragma unroll
    for (int u = 0; u < 16; u++){
      cf o = shflx(v[u], 1);
      v[u] = h1 ? csb(o, v[u]) : cad(v[u], o);
    }
    bool h2 = (lo & 2) != 0;
    cf w2 = twid((float)(lo & 1) * 0.5f, 1.0f);
    #pragma unroll
    for (int u = 0; u < 16; u++){
      cf o = shflx(v[u], 2);
      cf whv = cml(w2, h2 ? v[u] : o);
      v[u] = h2 ? csb(o, whv) : cad(v[u], whv);
    }
    bool h4 = (lo & 4) != 0;
    cf w4 = twid((float)(lo & 3) * 0.25f, 1.0f);
    #pragma unroll
    for (int u = 0; u < 16; u++){
      cf o = shflx(v[u], 4);
      cf whv = cml(w4, h4 ? v[u] : o);
      v[u] = h4 ? csb(o, whv) : cad(v[u], whv);
    }
    bool h8 = (lo & 8) != 0;
    cf w8 = twid((float)(lo & 7) * 0.125f, 1.0f);
    #pragma unroll
    for (int u = 0; u < 16; u++){
      cf o = shflx(v[u], 8);
      cf whv = cml(w8, h8 ? v[u] : o);
      v[u] = h8 ? csb(o, whv) : cad(v[u], whv);
    }
  }
  // stage B' (strides 16,32 then 64,128)
  {
    cf w1 = twid((float)lo * (1.0f/32.0f), 1.0f);
    #pragma unroll
    for (int g = 0; g < 16; g += 4)
      dit4q(v[g], v[g+1], v[g+2], v[g+3], w1, 1.0f);
  }
  #pragma unroll
  for (int u0 = 0; u0 < 4; u0++){
    cf w1 = twid((float)(16*u0 + lo) * (1.0f/128.0f), 1.0f);
    dit4q(v[u0], v[u0+4], v[u0+8], v[u0+12], w1, 1.0f);
  }
  // T1'
  #pragma unroll
  for (int u = 0; u < 16; u++) c[m1 + 16*u] = v[u];
  __syncthreads();
  #pragma unroll
  for (int r = 0; r < 16; r++) v[r] = c[t + 260*r];
  // stage A' (strides 256,512 then 1024,2048)
  {
    cf w1 = twid((float)t * (1.0f/512.0f), 1.0f);
    #pragma unroll
    for (int g = 0; g < 16; g += 4)
      dit4q(v[g], v[g+1], v[g+2], v[g+3], w1, 1.0f);
  }
  #pragma unroll
  for (int r0 = 0; r0 < 4; r0++){
    cf w1 = twid((float)(t + 256*r0) * (1.0f/2048.0f), 1.0f);
    dit4q(v[r0], v[r0+4], v[r0+8], v[r0+12], w1, 1.0f);
  }
}

// ---------------- init atomic-max buffers ----------------
__global__ void k_init(unsigned* xmax, unsigned* ymax){
  int i = blockIdx.x * 256 + threadIdx.x;
  if (i < 2048){ xmax[i] = 0u; ymax[i] = 0u; }
}

// ---------------- transpose x (B,L,H)->(B,H,L), fused max|x| ----------------
__global__ __launch_bounds__(256) void k_transpose_x(const float* __restrict__ x,
                                                     float* __restrict__ xT,
                                                     unsigned* __restrict__ xmax){
  __shared__ float tile[64][65];
  __shared__ float red[64][4];
  int b = blockIdx.z;
  int t0 = blockIdx.x * 64;
  int h0 = blockIdx.y * 64;
  int hc = threadIdx.x & 63, tg = threadIdx.x >> 6;
  float pmax = 0.0f;
  #pragma unroll
  for (int q = 0; q < 16; q++){
    int tr = tg + q * 4;
    float v = x[((size_t)(b * 4096 + t0 + tr)) * 256 + h0 + hc];
    tile[tr][hc] = v;
    pmax = fmaxf(pmax, fabsf(v));
  }
  red[hc][tg] = pmax;
  __syncthreads();
  if (threadIdx.x < 64){
    float m = fmaxf(fmaxf(red[threadIdx.x][0], red[threadIdx.x][1]),
                    fmaxf(red[threadIdx.x][2], red[threadIdx.x][3]));
    atomicMax(&xmax[b * 256 + h0 + threadIdx.x], __float_as_uint(m));
  }
  #pragma unroll
  for (int q = 0; q < 16; q++){
    int hr = tg + q * 4;
    xT[((size_t)(b * 256 + h0 + hr)) * 4096 + t0 + hc] = tile[hc][hr];
  }
}

// ---------------- W -> bf16 hi/lo planes ----------------
__global__ void k_wsplit(const float* __restrict__ W, ushort* __restrict__ Wh, ushort* __restrict__ Wl){
  int i = blockIdx.x * 256 + threadIdx.x;
  ushort h, l;
  bfsplit(W[i], &h, &l);
  Wh[i] = h; Wl[i] = l;
}

// ---------------- Cauchy / generating function ----------------
__global__ __launch_bounds__(256) void k_cauchy(
    const float* __restrict__ Lr, const float* __restrict__ Li,
    const float* __restrict__ Pr, const float* __restrict__ Pi,
    const float* __restrict__ Qr, const float* __restrict__ Qi,
    const float* __restrict__ Br, const float* __restrict__ Bi,
    const float* __restrict__ Cr, const float* __restrict__ Ci,
    const float* __restrict__ stepp, cf* __restrict__ A)
{
  __shared__ cf sLam[64], sB[64], sP[64], sQB[64], sQP[64];
  __shared__ cf sInv[64][16];
  __shared__ cf sWood[16], sC[16], sG[16];
  int tid = threadIdx.x;
  int l0 = blockIdx.x * 16;
  float stepv = fmaxf(stepp[0], 1e-6f);
  if (tid < 64){
    cf lam = cmk(Lr[tid], Li[tid]);
    cf b = cmk(Br[tid], Bi[tid]);
    cf p = cmk(Pr[tid], Pi[tid]);
    cf q = cmk(Qr[tid], Qi[tid]);
    sLam[tid] = lam; sB[tid] = b; sP[tid] = p;
    sQB[tid] = cml(q, b);
    sQP[tid] = cml(q, p);
  }
  __syncthreads();
  if (tid < 16){
    int l = l0 + tid;
    float ang = -6.2831855f * ((float)l * (1.0f / 4096.0f));
    cf Om = cmk(cosf(ang), sinf(ang));
    cf den = cmk(1.0f + Om.x, Om.y);
    cf num = cmk(1.0f - Om.x, -Om.y);
    cf rden = crcp(den);
    sC[tid] = cml(cmk(2.0f, 0.0f), rden);
    cf g = cml(num, rden);
    float sc = 2.0f / stepv;
    sG[tid] = cmk(g.x * sc, g.y * sc);
  }
  __syncthreads();
  for (int it = tid; it < 1024; it += 256){
    int n = it >> 4, ll = it & 15;
    sInv[n][ll] = crcp(csb(sG[ll], sLam[n]));
  }
  __syncthreads();
  if (tid < 16){
    cf k10 = cmk(0,0), k11 = cmk(0,0);
    for (int n = 0; n < 64; n++){
      k10 = cad(k10, cml(sQB[n], sInv[n][tid]));
      k11 = cad(k11, cml(sQP[n], sInv[n][tid]));
    }
    sWood[tid] = cdv(k10, cmk(1.0f + k11.x, k11.y));
  }
  __syncthreads();
  int h = tid;
  cf a0[16], a1[16];
  #pragma unroll
  for (int ll = 0; ll < 16; ll++){ a0[ll] = cmk(0,0); a1[ll] = cmk(0,0); }
  for (int n = 0; n < 64; n++){
    cf cc = cmk(Cr[h * 64 + n], Ci[h * 64 + n]);
    cf cb = cml(cc, sB[n]);
    cf cp = cml(cc, sP[n]);
    #pragma unroll
    for (int ll = 0; ll < 16; ll++){
      cf iv = sInv[n][ll];
      a0[ll] = cad(a0[ll], cml(cb, iv));
      a1[ll] = cad(a1[ll], cml(cp, iv));
    }
  }
  cf* dst = A + (size_t)h * 4096 + l0;
  #pragma unroll
  for (int ll = 0; ll < 16; ll++){
    dst[ll] = cml(sC[ll], csb(a0[ll], cml(a1[ll], sWood[ll])));
  }
}

// ---------------- S0 table (circular pass): Sa/Sb from symmetrized A, bitrev-paired ----------------
// record t<2048: slot p=2t, bin k=brev12(p). record 2048: slot 1, bin 2048.
__global__ __launch_bounds__(256) void k_s0(const cf* __restrict__ A, float4* __restrict__ S0){
  int hp = blockIdx.x;
  int rec = blockIdx.y * 256 + threadIdx.x;
  if (rec > 2048) return;
  int k = (rec < 2048) ? brev12(rec << 1) : 2048;
  int mk = (4096 - k) & 4095;
  const cf* a1p = A + (size_t)(2 * hp) * 4096;
  const cf* a2p = a1p + 4096;
  cf K1 = cad(a1p[k], cjg(a1p[mk]));   // 2*K1f[k]
  cf K2 = cad(a2p[k], cjg(a2p[mk]));
  const float s = 1.0f / 32768.0f;     // (1/2 sym)*(1/2 Sa)*(1/4096 ifft)*(1/2 avg)
  S0[(size_t)hp * 2049 + rec] = make_float4((K1.x + K2.x) * s, (K1.y + K2.y) * s,
                                            (K1.x - K2.x) * s, (K1.y - K2.y) * s);
}

// ---------------- T table (negacyclic pass): DIT4096(A) -> twist -> DIF4096 -> pair-unpack ----------------
__global__ __launch_bounds__(256) void k_kf(const cf* __restrict__ A, float4* __restrict__ Tt){
  extern __shared__ cf c[];    // 4096 cf
  int hp = blockIdx.x, tid = threadIdx.x;
  const cf* a1p = A + (size_t)(2 * hp) * 4096;
  const cf* a2p = a1p + 4096;
  for (int l = tid; l < 4096; l += TPB){
    int r = brev12(l);
    cf u = a1p[l], w = a2p[l];
    c[r] = cmk(u.x - w.y, u.y + w.x);          // A1 + i*A2, bitrev order
  }
  fft_dit_r4<4096>(c, 1.0f);                   // -> 4096*(k1 + i*k2), natural
  const float inv = 1.0f / 4096.0f;
  for (int l = tid; l < 4096; l += TPB){
    cf tw = twid((float)l * inv, -1.0f);       // tau[l]
    tw.x *= inv; tw.y *= inv;
    c[l] = cml(c[l], tw);
  }
  fft_dif_r4<4096, 1024>(c, -1.0f);            // Z = FFT(K~ * tau), bitrev order
  float4* rec = Tt + (size_t)hp * 2048;
  const float st = 1.0f / 32768.0f;            // (1/2 unpack)*(1/2 Ta)*(1/4096)*(1/2 avg)
  #pragma unroll
  for (int q8 = 0; q8 < 8; q8++){
    int tr = tid + 256 * q8;
    int p = tr << 1;
    int k = brev12(p);
    int qs = brev12(4095 - k);
    cf Zp = c[p], Zq = c[qs];
    float G1x = Zp.x + Zq.x, G1y = Zp.y - Zq.y;   // 2*G1
    float dx = Zp.x - Zq.x, dy = Zp.y + Zq.y;
    float G2x = dy, G2y = -dx;                    // 2*G2
    rec[tr] = make_float4((G1x + G2x) * st, (G1y + G2y) * st,
                          (G1x - G2x) * st, (G1y - G2y) * st);
  }
}

// ---------------- conv: circular+negacyclic 4096 register FFTs, 2 channels/block ----------------
__global__ __launch_bounds__(256, 4) void k_conv(const float* __restrict__ xT,
                                                 const float4* __restrict__ S0,
                                                 const float4* __restrict__ Tt,
                                                 const float* __restrict__ Dp,
                                                 ushort* __restrict__ y1h,
                                                 ushort* __restrict__ y1l){
  __shared__ cf c[4160];
  int blk = blockIdx.x;
  int b = blk >> 7, hp = blk & 127;
  int t = threadIdx.x, lo = t & 15;
  const float* xs1 = xT + ((size_t)(b * 256 + 2 * hp)) * 4096;
  const float* xs2 = xs1 + 4096;
  cf xv[16], v[16];
  #pragma unroll
  for (int r = 0; r < 16; r++){
    int n = t + 256 * r;
    xv[r] = cmk(xs1[n], xs2[n]);
    v[r] = xv[r];
  }
  // ---- pass 0: circular ----
  dif4096_reg(v, c, t, lo);
  {
    const float4* rec0 = S0 + (size_t)hp * 2049;
    #pragma unroll
    for (int q8 = 0; q8 < 8; q8++){
      int tr = t + 256 * q8;
      int p = tr << 1;
      int k = brev12(p);
      int q0 = brev12((4096 - k) & 4095);
      int pi = p + 4 * (p >> 8), qi = q0 + 4 * (q0 >> 8);
      cf Zp = c[pi], Zq = c[qi];
      float4 r0 = rec0[tr];
      cf Sa = cmk(r0.x, r0.y), Sb = cmk(r0.z, r0.w);
      c[pi] = cad(cml(Zp, Sa), cml(cjg(Zq), Sb));
      c[qi] = cad(cml(Zq, cjg(Sa)), cml(cjg(Zp), cjg(Sb)));
    }
    if (t == 0){
      float4 e = rec0[2048];
      cf Z1 = c[1];
      c[1] = cad(cml(Z1, cmk(e.x, e.y)), cml(cjg(Z1), cmk(e.z, e.w)));
    }
  }
  __syncthreads();
  dit4096_reg(v, c, t, lo);
  cf acc[16];
  #pragma unroll
  for (int r = 0; r < 16; r++) acc[r] = v[r];
  // ---- pass 1: negacyclic (pre-twist) ----
  #pragma unroll
  for (int r = 0; r < 16; r++){
    int n = t + 256 * r;
    v[r] = cml(xv[r], twid((float)n * (1.0f / 4096.0f), -1.0f));
  }
  dif4096_reg(v, c, t, lo);
  {
    const float4* rec1 = Tt + (size_t)hp * 2048;
    #pragma unroll
    for (int q8 = 0; q8 < 8; q8++){
      int tr = t + 256 * q8;
      int p = tr << 1;
      int k = brev12(p);
      int q1 = brev12(4095 - k);
      int pi = p + 4 * (p >> 8), qi = q1 + 4 * (q1 >> 8);
      cf Zp = c[pi], Zq = c[qi];
      float4 r0 = rec1[tr];
      cf Ta = cmk(r0.x, r0.y), Tb = cmk(r0.z, r0.w);
      c[pi] = cad(cml(Zp, Ta), cml(cjg(Zq), Tb));
      c[qi] = cad(cml(Zq, cjg(Ta)), cml(cjg(Zp), cjg(Tb)));
    }
  }
  __syncthreads();
  dit4096_reg(v, c, t, lo);
  // ---- combine (post-twist pass1) + epilogue ----
  float Dv = Dp[0];
  size_t base = ((size_t)(b * 256 + 2 * hp)) * 4096;
  #pragma unroll
  for (int r = 0; r < 16; r++){
    int n = t + 256 * r;
    cf u = cml(v[r], twid((float)n * (1.0f / 4096.0f), 1.0f));  // conj(tau)
    float y1 = acc[r].x + u.x;
    float y2 = acc[r].y + u.y;
    float z1 = geluf(fmaf(Dv, xs1[n], y1));
    float z2 = geluf(fmaf(Dv, xs2[n], y2));
    ushort h0, l0, h1u, l1;
    bfsplit(z1, &h0, &l0);
    bfsplit(z2, &h1u, &l1);
    y1h[base + n] = h0;         y1l[base + n] = l0;
    y1h[base + 4096 + n] = h1u; y1l[base + 4096 + n] = l1;
  }
}

// ---------------- MFMA split-bf16 GEMM + gelu + skip + LayerNorm + max|y| ----------------
__global__ __launch_bounds__(256, 3) void k_gemm_ln(
    const ushort* __restrict__ y1h, const ushort* __restrict__ y1l,
    const ushort* __restrict__ Wh, const ushort* __restrict__ Wl,
    const float* __restrict__ bfc, const float* __restrict__ x,
    const float* __restrict__ lng, const float* __restrict__ lnb,
    float* __restrict__ yout, unsigned* __restrict__ ymax)
{
  __shared__ ushort sY[2][64 * 40];
  __shared__ float red1[64][4], red2[64][4];
  int tid = threadIdx.x;
  int l = tid & 63;
  int w = tid >> 6;
  int blk = blockIdx.x;
  int b = blk >> 6;
  int t0 = (blk & 63) * 64;
  int g = l >> 4, cc = l & 15;

  f32x4 acc[4][4];
  #pragma unroll
  for (int m = 0; m < 4; m++)
    #pragma unroll
    for (int n = 0; n < 4; n++)
      acc[m][n] = (f32x4){0.0f, 0.0f, 0.0f, 0.0f};

  int kk = tid >> 3, ts = (tid & 7) * 8;

  #pragma unroll 1
  for (int kc = 0; kc < 256; kc += 32){
    __syncthreads();
    {
      size_t gb = ((size_t)(b * 256 + kc + kk)) * 4096 + t0 + ts;
      float4 vh = *(const float4*)(y1h + gb);
      float4 vl = *(const float4*)(y1l + gb);
      const ushort* ph = (const ushort*)&vh;
      const ushort* pl = (const ushort*)&vl;
      int kblk = kk >> 3, kin = kk & 7;
      #pragma unroll
      for (int e = 0; e < 8; e++){
        int t = ts + e;
        int idx = t * 40 + ((kblk ^ ((t >> 3) & 3)) << 3) + kin;
        sY[0][idx] = ph[e];
        sY[1][idx] = pl[e];
      }
    }
    __syncthreads();
    bf16x8 afh[4], afl[4];
    #pragma unroll
    for (int m = 0; m < 4; m++){
      int t = m * 16 + cc;
      int idx = t * 40 + ((g ^ ((t >> 3) & 3)) << 3);
      afh[m] = *(bf16x8*)&sY[0][idx];
      afl[m] = *(bf16x8*)&sY[1][idx];
    }
    #pragma unroll
    for (int n = 0; n < 4; n++){
      size_t wj = (size_t)(w * 64 + n * 16 + cc) * 256 + kc + g * 8;
      bf16x8 bh = *(const bf16x8*)(Wh + wj);
      bf16x8 bl = *(const bf16x8*)(Wl + wj);
      #pragma unroll
      for (int m = 0; m < 4; m++){
        acc[m][n] = __builtin_amdgcn_mfma_f32_16x16x32_bf16(afh[m], bh, acc[m][n], 0, 0, 0);
        acc[m][n] = __builtin_amdgcn_mfma_f32_16x16x32_bf16(afh[m], bl, acc[m][n], 0, 0, 0);
        acc[m][n] = __builtin_amdgcn_mfma_f32_16x16x32_bf16(afl[m], bh, acc[m][n], 0, 0, 0);
      }
    }
  }

  float bj[4], gj[4], lj[4];
  #pragma unroll
  for (int n = 0; n < 4; n++){
    int j = w * 64 + n * 16 + cc;
    bj[n] = bfc[j]; gj[n] = lng[j]; lj[n] = lnb[j];
  }
  #pragma unroll
  for (int m = 0; m < 4; m++){
    #pragma unroll
    for (int r = 0; r < 4; r++){
      int tl = m * 16 + g * 4 + r;
      size_t rowb = ((size_t)(b * 4096 + t0 + tl)) * 256;
      float ss = 0.0f, sq = 0.0f;
      #pragma unroll
      for (int n = 0; n < 4; n++){
        float z = geluf(acc[m][n][r] + bj[n]) + x[rowb + w * 64 + n * 16 + cc];
        acc[m][n][r] = z;
        ss += z; sq = fmaf(z, z, sq);
      }
      #pragma unroll
      for (int msk = 1; msk < 16; msk <<= 1){
        ss += __shfl_xor(ss, msk);
        sq += __shfl_xor(sq, msk);
      }
      if (cc == 0){ red1[tl][w] = ss; red2[tl][w] = sq; }
    }
  }
  __syncthreads();
  float jm[4] = {0.0f, 0.0f, 0.0f, 0.0f};
  #pragma unroll
  for (int m = 0; m < 4; m++){
    #pragma unroll
    for (int r = 0; r < 4; r++){
      int tl = m * 16 + g * 4 + r;
      float ts1 = red1[tl][0] + red1[tl][1] + red1[tl][2] + red1[tl][3];
      float ts2 = red2[tl][0] + red2[tl][1] + red2[tl][2] + red2[tl][3];
      float mu = ts1 * (1.0f / 256.0f);
      float var = ts2 * (1.0f / 256.0f) - mu * mu;
      float rstd = rsqrtf(var + 1e-5f);
      size_t rowb = ((size_t)(b * 4096 + t0 + tl)) * 256;
      #pragma unroll
      for (int n = 0; n < 4; n++){
        float yv = (acc[m][n][r] - mu) * rstd * gj[n] + lj[n];
        yout[rowb + w * 64 + n * 16 + cc] = yv;
        jm[n] = fmaxf(jm[n], fabsf(yv));
      }
    }
  }
  #pragma unroll
  for (int n = 0; n < 4; n++){
    jm[n] = fmaxf(jm[n], __shfl_xor(jm[n], 16));
    jm[n] = fmaxf(jm[n], __shfl_xor(jm[n], 32));
  }
  if (g == 0){
    #pragma unroll
    for (int n = 0; n < 4; n++)
      atomicMax(&ymax[b * 256 + w * 64 + n * 16 + cc], __float_as_uint(jm[n]));
  }
}

// ---------------- final ratio ----------------
__global__ void k_ratio(const unsigned* __restrict__ ymax, const unsigned* __restrict__ xmax,
                        float* __restrict__ out){
  int i = blockIdx.x * 256 + threadIdx.x;
  if (i < 2048){
    float ym = __uint_as_float(ymax[i]);
    float xm = __uint_as_float(xmax[i]);
    out[8388608 + i] = ym / (xm + 1e-6f);
  }
}

extern "C" void kernel_launch(void* const* d_in, const int* in_sizes, int n_in,
                              void* d_out, int out_size, void* d_ws, size_t ws_size,
                              hipStream_t stream)
{
  const float* x    = (const float*)d_in[0];
  const float* Lr   = (const float*)d_in[1];
  const float* Li   = (const float*)d_in[2];
  const float* Pr   = (const float*)d_in[3];
  const float* Pi   = (const float*)d_in[4];
  const float* Qr   = (const float*)d_in[5];
  const float* Qi   = (const float*)d_in[6];
  const float* Br   = (const float*)d_in[7];
  const float* Bi   = (const float*)d_in[8];
  const float* Cr   = (const float*)d_in[9];
  const float* Ci   = (const float*)d_in[10];
  const float* stp  = (const float*)d_in[11];
  const float* Dp   = (const float*)d_in[12];
  const float* Wfc  = (const float*)d_in[13];
  const float* bfc  = (const float*)d_in[14];
  const float* lng  = (const float*)d_in[15];
  const float* lnb  = (const float*)d_in[16];

  char* ws = (char*)d_ws;
  float*    xT   = (float*)(ws);                                     // 32 MB
  float4*   S0   = (float4*)(ws + ((size_t)32 << 20));               // ~4.0 MB (128*2049*16)
  float4*   Tt   = (float4*)(ws + ((size_t)36 << 20) + (512u << 10));// 4 MB (128*2048*16)
  cf*       A    = (cf*)(ws + ((size_t)41 << 20));                   // 8 MB (dead after k_kf/k_s0)
  ushort*   y1h  = (ushort*)(ws + ((size_t)41 << 20));               // 16 MB (overlays A)
  ushort*   y1l  = (ushort*)(ws + ((size_t)57 << 20));               // 16 MB
  ushort*   Wh   = (ushort*)(ws + ((size_t)73 << 20));               // 128 KB
  ushort*   Wl   = (ushort*)(ws + ((size_t)73 << 20) + (128u << 10));
  unsigned* xmax = (unsigned*)(ws + ((size_t)73 << 20) + (256u << 10));
  unsigned* ymax = xmax + 2048;

  k_init<<<8, 256, 0, stream>>>(xmax, ymax);
  dim3 gt(64, 4, 8);
  k_transpose_x<<<gt, 256, 0, stream>>>(x, xT, xmax);
  k_wsplit<<<256, 256, 0, stream>>>(Wfc, Wh, Wl);
  k_cauchy<<<256, 256, 0, stream>>>(Lr, Li, Pr, Pi, Qr, Qi, Br, Bi, Cr, Ci, stp, A);
  k_s0<<<dim3(128, 9), 256, 0, stream>>>(A, S0);
  k_kf<<<128, 256, 32768, stream>>>(A, Tt);
  k_conv<<<1024, 256, 0, stream>>>(xT, S0, Tt, Dp, y1h, y1l);
  k_gemm_ln<<<512, 256, 0, stream>>>(y1h, y1l, Wh, Wl, bfc, x, lng, lnb, (float*)d_out, ymax);
  k_ratio<<<8, 256, 0, stream>>>(ymax, xmax, (float*)d_out);
}

// Round 6
// 251.351 us; speedup vs baseline: 1.4935x; 1.4935x over previous
//
#include <hip/hip_runtime.h>
#include <math.h>

#define TPB 256

typedef float2 cf;
typedef __attribute__((ext_vector_type(8))) short bf16x8;
typedef __attribute__((ext_vector_type(4))) float f32x4;

__device__ __forceinline__ cf cmk(float x, float y){ cf r; r.x=x; r.y=y; return r; }
__device__ __forceinline__ cf cml(cf a, cf b){ return cmk(a.x*b.x - a.y*b.y, a.x*b.y + a.y*b.x); }
__device__ __forceinline__ cf cad(cf a, cf b){ return cmk(a.x+b.x, a.y+b.y); }
__device__ __forceinline__ cf csb(cf a, cf b){ return cmk(a.x-b.x, a.y-b.y); }
__device__ __forceinline__ cf cjg(cf a){ return cmk(a.x, -a.y); }
__device__ __forceinline__ cf crcp(cf d){ float r = 1.0f/(d.x*d.x + d.y*d.y); return cmk(d.x*r, -d.y*r); }
__device__ __forceinline__ cf cdv(cf n, cf d){ return cml(n, crcp(d)); }
__device__ __forceinline__ float geluf(float z){ return 0.5f*z*(1.0f + erff(z*0.70710678118654752f)); }

// exp(sign*i*pi*f) via native v_sin/v_cos (input in revolutions)
__device__ __forceinline__ cf twid(float f, float sign){
  float h = f * 0.5f;
  float s = __builtin_amdgcn_sinf(h);
  float c0 = __builtin_amdgcn_cosf(h);
  return cmk(c0, sign * s);
}

__device__ __forceinline__ cf shflx(cf v, int m){
  return cmk(__shfl_xor(v.x, m), __shfl_xor(v.y, m));
}

__device__ __forceinline__ void bfsplit(float v, ushort* h, ushort* l){
  unsigned u = __float_as_uint(v);
  unsigned hr = (u + 0x7FFFu + ((u >> 16) & 1u)) & 0xFFFF0000u;
  *h = (ushort)(hr >> 16);
  float lv = v - __uint_as_float(hr);
  unsigned u2 = __float_as_uint(lv);
  *l = (ushort)((u2 + 0x7FFFu + ((u2 >> 16) & 1u)) >> 16);
}

// radix-4 butterflies on a register quad (strides 0,s,2s,3s), w1 = W(j, 4s)
__device__ __forceinline__ void dif4q(cf& q0, cf& q1, cf& q2, cf& q3, cf w1, float sign){
  cf w2 = cml(w1, w1);
  cf a1 = cad(q0, q2);
  cf c1 = cml(csb(q0, q2), w1);
  cf b1 = cad(q1, q3);
  cf d1 = cml(csb(q1, q3), cmk(-sign*w1.y, sign*w1.x));
  q0 = cad(a1, b1);
  q1 = cml(csb(a1, b1), w2);
  q2 = cad(c1, d1);
  q3 = cml(csb(c1, d1), w2);
}
__device__ __forceinline__ void dit4q(cf& q0, cf& q1, cf& q2, cf& q3, cf w1, float sign){
  cf w2 = cml(w1, w1);
  cf t1 = cml(q1, w2);
  cf a1 = cad(q0, t1), b1 = csb(q0, t1);
  cf t2 = cml(q3, w2);
  cf c1 = cad(q2, t2), d1 = csb(q2, t2);
  cf v1 = cml(c1, w1);
  cf v2 = cml(d1, cmk(-sign*w1.y, sign*w1.x));
  q0 = cad(a1, v1);
  q2 = csb(a1, v1);
  q1 = cad(b1, v2);
  q3 = csb(b1, v2);
}

// ---------------- legacy LDS FFT templates (used by k_kf, N=4096) ----------------
template<int N, int SSTART>
__device__ void fft_dif_r4(cf* __restrict__ a, float sign){
  #pragma unroll
  for (int s = SSTART; s >= 1; s >>= 2){
    __syncthreads();
    #pragma unroll
    for (int g = 0; g < (N >> 2) / TPB; g++){
      int w = (int)threadIdx.x + g * TPB;
      int j = w & (s - 1);
      int base = ((w & ~(s - 1)) << 2) | j;
      cf A0 = a[base], B0 = a[base + s], C0 = a[base + 2*s], D0 = a[base + 3*s];
      cf w1 = twid((float)j / (float)(2 * s), sign);
      cf w2 = cml(w1, w1);
      cf a1 = cad(A0, C0);
      cf c1 = cml(csb(A0, C0), w1);
      cf b1 = cad(B0, D0);
      cf d1 = cml(csb(B0, D0), cmk(-sign * w1.y, sign * w1.x));
      a[base]         = cad(a1, b1);
      a[base + s]     = cml(csb(a1, b1), w2);
      a[base + 2*s]   = cad(c1, d1);
      a[base + 3*s]   = cml(csb(c1, d1), w2);
    }
  }
  if constexpr ((__builtin_ctz(N) & 1) == 1){
    __syncthreads();
    #pragma unroll
    for (int g = 0; g < (N >> 1) / TPB; g++){
      int w = (int)threadIdx.x + g * TPB;
      int i = w << 1;
      cf u = a[i], v = a[i + 1];
      a[i] = cad(u, v);
      a[i + 1] = csb(u, v);
    }
  }
  __syncthreads();
}

template<int N>
__device__ void fft_dit_r4(cf* __restrict__ a, float sign){
  if constexpr ((__builtin_ctz(N) & 1) == 1){
    __syncthreads();
    #pragma unroll
    for (int g = 0; g < (N >> 1) / TPB; g++){
      int w = (int)threadIdx.x + g * TPB;
      int i = w << 1;
      cf u = a[i], v = a[i + 1];
      a[i] = cad(u, v);
      a[i + 1] = csb(u, v);
    }
  }
  constexpr int S0 = ((__builtin_ctz(N) & 1) == 1) ? 2 : 1;
  #pragma unroll
  for (int s = S0; s <= (N >> 2); s <<= 2){
    __syncthreads();
    #pragma unroll
    for (int g = 0; g < (N >> 2) / TPB; g++){
      int w = (int)threadIdx.x + g * TPB;
      int j = w & (s - 1);
      int base = ((w & ~(s - 1)) << 2) | j;
      cf A0 = a[base], B0 = a[base + s], C0 = a[base + 2*s], D0 = a[base + 3*s];
      cf w1 = twid((float)j / (float)(2 * s), sign);
      cf w2 = cml(w1, w1);
      cf t1 = cml(B0, w2);
      cf a1 = cad(A0, t1), b1 = csb(A0, t1);
      cf t2 = cml(D0, w2);
      cf c1 = cad(C0, t2), d1 = csb(C0, t2);
      cf v1 = cml(c1, w1);
      cf v2 = cml(d1, cmk(-sign * w1.y, sign * w1.x));
      a[base]         = cad(a1, v1);
      a[base + 2*s]   = csb(a1, v1);
      a[base + s]     = cad(b1, v2);
      a[base + 3*s]   = csb(b1, v2);
    }
  }
  __syncthreads();
}

__device__ __forceinline__ int brev12(int x){ return (int)(__brev((unsigned)x) >> 20); }

// ---------------- register FFT4096: M0 (slot n = t+256r) <-> M1 (n = 256(t>>4)+16u+(t&15)) ----------------
// LDS idx(n) = n + 4*(n>>8); buffer 4160 cf (33,280 B)

__device__ __forceinline__ void dif4096_reg(cf (&v)[16], cf* __restrict__ c, int t, int lo){
  // stage A (bits 11..8)
  #pragma unroll
  for (int r0 = 0; r0 < 4; r0++){
    cf w1 = twid((float)(t + 256*r0) * (1.0f/2048.0f), -1.0f);
    dif4q(v[r0], v[r0+4], v[r0+8], v[r0+12], w1, -1.0f);
  }
  {
    cf w1 = twid((float)t * (1.0f/512.0f), -1.0f);
    #pragma unroll
    for (int g = 0; g < 16; g += 4)
      dif4q(v[g], v[g+1], v[g+2], v[g+3], w1, -1.0f);
  }
  // T1
  __syncthreads();
  #pragma unroll
  for (int r = 0; r < 16; r++) c[t + 260*r] = v[r];
  __syncthreads();
  int m1 = (t >> 4) * 260 + lo;
  #pragma unroll
  for (int u = 0; u < 16; u++) v[u] = c[m1 + 16*u];
  // stage B (bits 7..4)
  #pragma unroll
  for (int u0 = 0; u0 < 4; u0++){
    cf w1 = twid((float)(16*u0 + lo) * (1.0f/128.0f), -1.0f);
    dif4q(v[u0], v[u0+4], v[u0+8], v[u0+12], w1, -1.0f);
  }
  {
    cf w1 = twid((float)lo * (1.0f/32.0f), -1.0f);
    #pragma unroll
    for (int g = 0; g < 16; g += 4)
      dif4q(v[g], v[g+1], v[g+2], v[g+3], w1, -1.0f);
  }
  // stage C (bits 3..0 via shuffles)
  {
    bool h8 = (lo & 8) != 0;
    cf tw8 = twid((float)(lo & 7) * 0.125f, -1.0f);
    #pragma unroll
    for (int u = 0; u < 16; u++){
      cf o = shflx(v[u], 8);
      v[u] = h8 ? cml(csb(o, v[u]), tw8) : cad(v[u], o);
    }
    bool h4 = (lo & 4) != 0;
    cf tw4 = twid((float)(lo & 3) * 0.25f, -1.0f);
    #pragma unroll
    for (int u = 0; u < 16; u++){
      cf o = shflx(v[u], 4);
      v[u] = h4 ? cml(csb(o, v[u]), tw4) : cad(v[u], o);
    }
    bool h2 = (lo & 2) != 0;
    cf tw2 = twid((float)(lo & 1) * 0.5f, -1.0f);
    #pragma unroll
    for (int u = 0; u < 16; u++){
      cf o = shflx(v[u], 2);
      v[u] = h2 ? cml(csb(o, v[u]), tw2) : cad(v[u], o);
    }
    bool h1 = (lo & 1) != 0;
    #pragma unroll
    for (int u = 0; u < 16; u++){
      cf o = shflx(v[u], 1);
      v[u] = h1 ? csb(o, v[u]) : cad(v[u], o);
    }
  }
  // write M1 for pointwise
  #pragma unroll
  for (int u = 0; u < 16; u++) c[m1 + 16*u] = v[u];
  __syncthreads();
}

__device__ __forceinline__ void dit4096_reg(cf (&v)[16], cf* __restrict__ c, int t, int lo){
  int m1 = (t >> 4) * 260 + lo;
  #pragma unroll
  for (int u = 0; u < 16; u++) v[u] = c[m1 + 16*u];
  // stage C' (strides 1,2,4,8)
  {
    bool h1 = (lo & 1) != 0;
    #pragma unroll
    for (int u = 0; u < 16; u++){
      cf o = shflx(v[u], 1);
      v[u] = h1 ? csb(o, v[u]) : cad(v[u], o);
    }
    bool h2 = (lo & 2) != 0;
    cf w2 = twid((float)(lo & 1) * 0.5f, 1.0f);
    #pragma unroll
    for (int u = 0; u < 16; u++){
      cf o = shflx(v[u], 2);
      cf whv = cml(w2, h2 ? v[u] : o);
      v[u] = h2 ? csb(o, whv) : cad(v[u], whv);
    }
    bool h4 = (lo & 4) != 0;
    cf w4 = twid((float)(lo & 3) * 0.25f, 1.0f);
    #pragma unroll
    for (int u = 0; u < 16; u++){
      cf o = shflx(v[u], 4);
      cf whv = cml(w4, h4 ? v[u] : o);
      v[u] = h4 ? csb(o, whv) : cad(v[u], whv);
    }
    bool h8 = (lo & 8) != 0;
    cf w8 = twid((float)(lo & 7) * 0.125f, 1.0f);
    #pragma unroll
    for (int u = 0; u < 16; u++){
      cf o = shflx(v[u], 8);
      cf whv = cml(w8, h8 ? v[u] : o);
      v[u] = h8 ? csb(o, whv) : cad(v[u], whv);
    }
  }
  // stage B' (strides 16,32 then 64,128)
  {
    cf w1 = twid((float)lo * (1.0f/32.0f), 1.0f);
    #pragma unroll
    for (int g = 0; g < 16; g += 4)
      dit4q(v[g], v[g+1], v[g+2], v[g+3], w1, 1.0f);
  }
  #pragma unroll
  for (int u0 = 0; u0 < 4; u0++){
    cf w1 = twid((float)(16*u0 + lo) * (1.0f/128.0f), 1.0f);
    dit4q(v[u0], v[u0+4], v[u0+8], v[u0+12], w1, 1.0f);
  }
  // T1'
  #pragma unroll
  for (int u = 0; u < 16; u++) c[m1 + 16*u] = v[u];
  __syncthreads();
  #pragma unroll
  for (int r = 0; r < 16; r++) v[r] = c[t + 260*r];
  // stage A' (strides 256,512 then 1024,2048)
  {
    cf w1 = twid((float)t * (1.0f/512.0f), 1.0f);
    #pragma unroll
    for (int g = 0; g < 16; g += 4)
      dit4q(v[g], v[g+1], v[g+2], v[g+3], w1, 1.0f);
  }
  #pragma unroll
  for (int r0 = 0; r0 < 4; r0++){
    cf w1 = twid((float)(t + 256*r0) * (1.0f/2048.0f), 1.0f);
    dit4q(v[r0], v[r0+4], v[r0+8], v[r0+12], w1, 1.0f);
  }
}

// ---------------- init atomic-max buffers ----------------
__global__ void k_init(unsigned* xmax, unsigned* ymax){
  int i = blockIdx.x * 256 + threadIdx.x;
  if (i < 2048){ xmax[i] = 0u; ymax[i] = 0u; }
}

// ---------------- transpose x (B,L,H)->(B,H,L), fused max|x| ----------------
__global__ __launch_bounds__(256) void k_transpose_x(const float* __restrict__ x,
                                                     float* __restrict__ xT,
                                                     unsigned* __restrict__ xmax){
  __shared__ float tile[64][65];
  __shared__ float red[64][4];
  int b = blockIdx.z;
  int t0 = blockIdx.x * 64;
  int h0 = blockIdx.y * 64;
  int hc = threadIdx.x & 63, tg = threadIdx.x >> 6;
  float pmax = 0.0f;
  #pragma unroll
  for (int q = 0; q < 16; q++){
    int tr = tg + q * 4;
    float v = x[((size_t)(b * 4096 + t0 + tr)) * 256 + h0 + hc];
    tile[tr][hc] = v;
    pmax = fmaxf(pmax, fabsf(v));
  }
  red[hc][tg] = pmax;
  __syncthreads();
  if (threadIdx.x < 64){
    float m = fmaxf(fmaxf(red[threadIdx.x][0], red[threadIdx.x][1]),
                    fmaxf(red[threadIdx.x][2], red[threadIdx.x][3]));
    atomicMax(&xmax[b * 256 + h0 + threadIdx.x], __float_as_uint(m));
  }
  #pragma unroll
  for (int q = 0; q < 16; q++){
    int hr = tg + q * 4;
    xT[((size_t)(b * 256 + h0 + hr)) * 4096 + t0 + hc] = tile[hc][hr];
  }
}

// ---------------- W -> bf16 hi/lo planes ----------------
__global__ void k_wsplit(const float* __restrict__ W, ushort* __restrict__ Wh, ushort* __restrict__ Wl){
  int i = blockIdx.x * 256 + threadIdx.x;
  ushort h, l;
  bfsplit(W[i], &h, &l);
  Wh[i] = h; Wl[i] = l;
}

// ---------------- Cauchy / generating function ----------------
__global__ __launch_bounds__(256) void k_cauchy(
    const float* __restrict__ Lr, const float* __restrict__ Li,
    const float* __restrict__ Pr, const float* __restrict__ Pi,
    const float* __restrict__ Qr, const float* __restrict__ Qi,
    const float* __restrict__ Br, const float* __restrict__ Bi,
    const float* __restrict__ Cr, const float* __restrict__ Ci,
    const float* __restrict__ stepp, cf* __restrict__ A)
{
  __shared__ cf sLam[64], sB[64], sP[64], sQB[64], sQP[64];
  __shared__ cf sInv[64][16];
  __shared__ cf sWood[16], sC[16], sG[16];
  int tid = threadIdx.x;
  int l0 = blockIdx.x * 16;
  float stepv = fmaxf(stepp[0], 1e-6f);
  if (tid < 64){
    cf lam = cmk(Lr[tid], Li[tid]);
    cf b = cmk(Br[tid], Bi[tid]);
    cf p = cmk(Pr[tid], Pi[tid]);
    cf q = cmk(Qr[tid], Qi[tid]);
    sLam[tid] = lam; sB[tid] = b; sP[tid] = p;
    sQB[tid] = cml(q, b);
    sQP[tid] = cml(q, p);
  }
  __syncthreads();
  if (tid < 16){
    int l = l0 + tid;
    float ang = -6.2831855f * ((float)l * (1.0f / 4096.0f));
    cf Om = cmk(cosf(ang), sinf(ang));
    cf den = cmk(1.0f + Om.x, Om.y);
    cf num = cmk(1.0f - Om.x, -Om.y);
    cf rden = crcp(den);
    sC[tid] = cml(cmk(2.0f, 0.0f), rden);
    cf g = cml(num, rden);
    float sc = 2.0f / stepv;
    sG[tid] = cmk(g.x * sc, g.y * sc);
  }
  __syncthreads();
  for (int it = tid; it < 1024; it += 256){
    int n = it >> 4, ll = it & 15;
    sInv[n][ll] = crcp(csb(sG[ll], sLam[n]));
  }
  __syncthreads();
  if (tid < 16){
    cf k10 = cmk(0,0), k11 = cmk(0,0);
    for (int n = 0; n < 64; n++){
      k10 = cad(k10, cml(sQB[n], sInv[n][tid]));
      k11 = cad(k11, cml(sQP[n], sInv[n][tid]));
    }
    sWood[tid] = cdv(k10, cmk(1.0f + k11.x, k11.y));
  }
  __syncthreads();
  int h = tid;
  cf a0[16], a1[16];
  #pragma unroll
  for (int ll = 0; ll < 16; ll++){ a0[ll] = cmk(0,0); a1[ll] = cmk(0,0); }
  for (int n = 0; n < 64; n++){
    cf cc = cmk(Cr[h * 64 + n], Ci[h * 64 + n]);
    cf cb = cml(cc, sB[n]);
    cf cp = cml(cc, sP[n]);
    #pragma unroll
    for (int ll = 0; ll < 16; ll++){
      cf iv = sInv[n][ll];
      a0[ll] = cad(a0[ll], cml(cb, iv));
      a1[ll] = cad(a1[ll], cml(cp, iv));
    }
  }
  cf* dst = A + (size_t)h * 4096 + l0;
  #pragma unroll
  for (int ll = 0; ll < 16; ll++){
    dst[ll] = cml(sC[ll], csb(a0[ll], cml(a1[ll], sWood[ll])));
  }
}

// ---------------- S0 table (circular pass): Sa/Sb from symmetrized A, bitrev-paired ----------------
__global__ __launch_bounds__(256) void k_s0(const cf* __restrict__ A, float4* __restrict__ S0){
  int hp = blockIdx.x;
  int rec = blockIdx.y * 256 + threadIdx.x;
  if (rec > 2048) return;
  int k = (rec < 2048) ? brev12(rec << 1) : 2048;
  int mk = (4096 - k) & 4095;
  const cf* a1p = A + (size_t)(2 * hp) * 4096;
  const cf* a2p = a1p + 4096;
  cf K1 = cad(a1p[k], cjg(a1p[mk]));   // 2*K1f[k]
  cf K2 = cad(a2p[k], cjg(a2p[mk]));
  const float s = 1.0f / 32768.0f;
  S0[(size_t)hp * 2049 + rec] = make_float4((K1.x + K2.x) * s, (K1.y + K2.y) * s,
                                            (K1.x - K2.x) * s, (K1.y - K2.y) * s);
}

// ---------------- T table (negacyclic pass): DIT4096(A) -> twist -> DIF4096 -> pair-unpack ----------------
__global__ __launch_bounds__(256) void k_kf(const cf* __restrict__ A, float4* __restrict__ Tt){
  extern __shared__ cf c[];    // 4096 cf
  int hp = blockIdx.x, tid = threadIdx.x;
  const cf* a1p = A + (size_t)(2 * hp) * 4096;
  const cf* a2p = a1p + 4096;
  for (int l = tid; l < 4096; l += TPB){
    int r = brev12(l);
    cf u = a1p[l], w = a2p[l];
    c[r] = cmk(u.x - w.y, u.y + w.x);          // A1 + i*A2, bitrev order
  }
  fft_dit_r4<4096>(c, 1.0f);                   // -> 4096*(k1 + i*k2), natural
  const float inv = 1.0f / 4096.0f;
  for (int l = tid; l < 4096; l += TPB){
    cf tw = twid((float)l * inv, -1.0f);       // tau[l]
    tw.x *= inv; tw.y *= inv;
    c[l] = cml(c[l], tw);
  }
  fft_dif_r4<4096, 1024>(c, -1.0f);            // Z = FFT(K~ * tau), bitrev order
  float4* rec = Tt + (size_t)hp * 2048;
  const float st = 1.0f / 32768.0f;
  #pragma unroll
  for (int q8 = 0; q8 < 8; q8++){
    int tr = tid + 256 * q8;
    int p = tr << 1;
    int k = brev12(p);
    int qs = brev12(4095 - k);
    cf Zp = c[p], Zq = c[qs];
    float G1x = Zp.x + Zq.x, G1y = Zp.y - Zq.y;
    float dx = Zp.x - Zq.x, dy = Zp.y + Zq.y;
    float G2x = dy, G2y = -dx;
    rec[tr] = make_float4((G1x + G2x) * st, (G1y + G2y) * st,
                          (G1x - G2x) * st, (G1y - G2y) * st);
  }
}

// ---------------- conv: circular+negacyclic 4096 register FFTs, 2 channels/block ----------------
__global__ __launch_bounds__(256) void k_conv(const float* __restrict__ xT,
                                              const float4* __restrict__ S0,
                                              const float4* __restrict__ Tt,
                                              const float* __restrict__ Dp,
                                              ushort* __restrict__ y1h,
                                              ushort* __restrict__ y1l){
  __shared__ cf c[4160];
  int blk = blockIdx.x;
  int b = blk >> 7, hp = blk & 127;
  int t = threadIdx.x, lo = t & 15;
  const float* xs1 = xT + ((size_t)(b * 256 + 2 * hp)) * 4096;
  const float* xs2 = xs1 + 4096;
  cf v[16];
  #pragma unroll
  for (int r = 0; r < 16; r++){
    int n = t + 256 * r;
    v[r] = cmk(xs1[n], xs2[n]);
  }
  // ---- pass 0: circular ----
  dif4096_reg(v, c, t, lo);
  {
    const float4* rec0 = S0 + (size_t)hp * 2049;
    #pragma unroll
    for (int q8 = 0; q8 < 8; q8++){
      int tr = t + 256 * q8;
      int p = tr << 1;
      int k = brev12(p);
      int q0 = brev12((4096 - k) & 4095);
      int pi = p + 4 * (p >> 8), qi = q0 + 4 * (q0 >> 8);
      cf Zp = c[pi], Zq = c[qi];
      float4 r0 = rec0[tr];
      cf Sa = cmk(r0.x, r0.y), Sb = cmk(r0.z, r0.w);
      c[pi] = cad(cml(Zp, Sa), cml(cjg(Zq), Sb));
      c[qi] = cad(cml(Zq, cjg(Sa)), cml(cjg(Zp), cjg(Sb)));
    }
    if (t == 0){
      float4 e = rec0[2048];
      cf Z1 = c[1];
      c[1] = cad(cml(Z1, cmk(e.x, e.y)), cml(cjg(Z1), cmk(e.z, e.w)));
    }
  }
  __syncthreads();
  dit4096_reg(v, c, t, lo);
  cf acc[16];
  #pragma unroll
  for (int r = 0; r < 16; r++) acc[r] = v[r];
  // ---- pass 1: negacyclic (reload x + pre-twist) ----
  #pragma unroll
  for (int r = 0; r < 16; r++){
    int n = t + 256 * r;
    cf xv = cmk(xs1[n], xs2[n]);
    v[r] = cml(xv, twid((float)n * (1.0f / 4096.0f), -1.0f));
  }
  dif4096_reg(v, c, t, lo);
  {
    const float4* rec1 = Tt + (size_t)hp * 2048;
    #pragma unroll
    for (int q8 = 0; q8 < 8; q8++){
      int tr = t + 256 * q8;
      int p = tr << 1;
      int k = brev12(p);
      int q1 = brev12(4095 - k);
      int pi = p + 4 * (p >> 8), qi = q1 + 4 * (q1 >> 8);
      cf Zp = c[pi], Zq = c[qi];
      float4 r0 = rec1[tr];
      cf Ta = cmk(r0.x, r0.y), Tb = cmk(r0.z, r0.w);
      c[pi] = cad(cml(Zp, Ta), cml(cjg(Zq), Tb));
      c[qi] = cad(cml(Zq, cjg(Ta)), cml(cjg(Zp), cjg(Tb)));
    }
  }
  __syncthreads();
  dit4096_reg(v, c, t, lo);
  // ---- combine (post-twist pass1) + epilogue (reload x) ----
  float Dv = Dp[0];
  size_t base = ((size_t)(b * 256 + 2 * hp)) * 4096;
  #pragma unroll
  for (int r = 0; r < 16; r++){
    int n = t + 256 * r;
    cf u = cml(v[r], twid((float)n * (1.0f / 4096.0f), 1.0f));  // conj(tau)
    float y1 = acc[r].x + u.x;
    float y2 = acc[r].y + u.y;
    float z1 = geluf(fmaf(Dv, xs1[n], y1));
    float z2 = geluf(fmaf(Dv, xs2[n], y2));
    ushort h0, l0, h1u, l1;
    bfsplit(z1, &h0, &l0);
    bfsplit(z2, &h1u, &l1);
    y1h[base + n] = h0;         y1l[base + n] = l0;
    y1h[base + 4096 + n] = h1u; y1l[base + 4096 + n] = l1;
  }
}

// ---------------- MFMA split-bf16 GEMM + gelu + skip + LayerNorm + max|y| ----------------
__global__ __launch_bounds__(256, 3) void k_gemm_ln(
    const ushort* __restrict__ y1h, const ushort* __restrict__ y1l,
    const ushort* __restrict__ Wh, const ushort* __restrict__ Wl,
    const float* __restrict__ bfc, const float* __restrict__ x,
    const float* __restrict__ lng, const float* __restrict__ lnb,
    float* __restrict__ yout, unsigned* __restrict__ ymax)
{
  __shared__ ushort sY[2][64 * 40];
  __shared__ float red1[64][4], red2[64][4];
  int tid = threadIdx.x;
  int l = tid & 63;
  int w = tid >> 6;
  int blk = blockIdx.x;
  int b = blk >> 6;
  int t0 = (blk & 63) * 64;
  int g = l >> 4, cc = l & 15;

  f32x4 acc[4][4];
  #pragma unroll
  for (int m = 0; m < 4; m++)
    #pragma unroll
    for (int n = 0; n < 4; n++)
      acc[m][n] = (f32x4){0.0f, 0.0f, 0.0f, 0.0f};

  int kk = tid >> 3, ts = (tid & 7) * 8;

  #pragma unroll 1
  for (int kc = 0; kc < 256; kc += 32){
    __syncthreads();
    {
      size_t gb = ((size_t)(b * 256 + kc + kk)) * 4096 + t0 + ts;
      float4 vh = *(const float4*)(y1h + gb);
      float4 vl = *(const float4*)(y1l + gb);
      const ushort* ph = (const ushort*)&vh;
      const ushort* pl = (const ushort*)&vl;
      int kblk = kk >> 3, kin = kk & 7;
      #pragma unroll
      for (int e = 0; e < 8; e++){
        int t = ts + e;
        int idx = t * 40 + ((kblk ^ ((t >> 3) & 3)) << 3) + kin;
        sY[0][idx] = ph[e];
        sY[1][idx] = pl[e];
      }
    }
    __syncthreads();
    bf16x8 afh[4], afl[4];
    #pragma unroll
    for (int m = 0; m < 4; m++){
      int t = m * 16 + cc;
      int idx = t * 40 + ((g ^ ((t >> 3) & 3)) << 3);
      afh[m] = *(bf16x8*)&sY[0][idx];
      afl[m] = *(bf16x8*)&sY[1][idx];
    }
    #pragma unroll
    for (int n = 0; n < 4; n++){
      size_t wj = (size_t)(w * 64 + n * 16 + cc) * 256 + kc + g * 8;
      bf16x8 bh = *(const bf16x8*)(Wh + wj);
      bf16x8 bl = *(const bf16x8*)(Wl + wj);
      #pragma unroll
      for (int m = 0; m < 4; m++){
        acc[m][n] = __builtin_amdgcn_mfma_f32_16x16x32_bf16(afh[m], bh, acc[m][n], 0, 0, 0);
        acc[m][n] = __builtin_amdgcn_mfma_f32_16x16x32_bf16(afh[m], bl, acc[m][n], 0, 0, 0);
        acc[m][n] = __builtin_amdgcn_mfma_f32_16x16x32_bf16(afl[m], bh, acc[m][n], 0, 0, 0);
      }
    }
  }

  float bj[4], gj[4], lj[4];
  #pragma unroll
  for (int n = 0; n < 4; n++){
    int j = w * 64 + n * 16 + cc;
    bj[n] = bfc[j]; gj[n] = lng[j]; lj[n] = lnb[j];
  }
  #pragma unroll
  for (int m = 0; m < 4; m++){
    #pragma unroll
    for (int r = 0; r < 4; r++){
      int tl = m * 16 + g * 4 + r;
      size_t rowb = ((size_t)(b * 4096 + t0 + tl)) * 256;
      float ss = 0.0f, sq = 0.0f;
      #pragma unroll
      for (int n = 0; n < 4; n++){
        float z = geluf(acc[m][n][r] + bj[n]) + x[rowb + w * 64 + n * 16 + cc];
        acc[m][n][r] = z;
        ss += z; sq = fmaf(z, z, sq);
      }
      #pragma unroll
      for (int msk = 1; msk < 16; msk <<= 1){
        ss += __shfl_xor(ss, msk);
        sq += __shfl_xor(sq, msk);
      }
      if (cc == 0){ red1[tl][w] = ss; red2[tl][w] = sq; }
    }
  }
  __syncthreads();
  float jm[4] = {0.0f, 0.0f, 0.0f, 0.0f};
  #pragma unroll
  for (int m = 0; m < 4; m++){
    #pragma unroll
    for (int r = 0; r < 4; r++){
      int tl = m * 16 + g * 4 + r;
      float ts1 = red1[tl][0] + red1[tl][1] + red1[tl][2] + red1[tl][3];
      float ts2 = red2[tl][0] + red2[tl][1] + red2[tl][2] + red2[tl][3];
      float mu = ts1 * (1.0f / 256.0f);
      float var = ts2 * (1.0f / 256.0f) - mu * mu;
      float rstd = rsqrtf(var + 1e-5f);
      size_t rowb = ((size_t)(b * 4096 + t0 + tl)) * 256;
      #pragma unroll
      for (int n = 0; n < 4; n++){
        float yv = (acc[m][n][r] - mu) * rstd * gj[n] + lj[n];
        yout[rowb + w * 64 + n * 16 + cc] = yv;
        jm[n] = fmaxf(jm[n], fabsf(yv));
      }
    }
  }
  #pragma unroll
  for (int n = 0; n < 4; n++){
    jm[n] = fmaxf(jm[n], __shfl_xor(jm[n], 16));
    jm[n] = fmaxf(jm[n], __shfl_xor(jm[n], 32));
  }
  if (g == 0){
    #pragma unroll
    for (int n = 0; n < 4; n++)
      atomicMax(&ymax[b * 256 + w * 64 + n * 16 + cc], __float_as_uint(jm[n]));
  }
}

// ---------------- final ratio ----------------
__global__ void k_ratio(const unsigned* __restrict__ ymax, const unsigned* __restrict__ xmax,
                        float* __restrict__ out){
  int i = blockIdx.x * 256 + threadIdx.x;
  if (i < 2048){
    float ym = __uint_as_float(ymax[i]);
    float xm = __uint_as_float(xmax[i]);
    out[8388608 + i] = ym / (xm + 1e-6f);
  }
}

extern "C" void kernel_launch(void* const* d_in, const int* in_sizes, int n_in,
                              void* d_out, int out_size, void* d_ws, size_t ws_size,
                              hipStream_t stream)
{
  const float* x    = (const float*)d_in[0];
  const float* Lr   = (const float*)d_in[1];
  const float* Li   = (const float*)d_in[2];
  const float* Pr   = (const float*)d_in[3];
  const float* Pi   = (const float*)d_in[4];
  const float* Qr   = (const float*)d_in[5];
  const float* Qi   = (const float*)d_in[6];
  const float* Br   = (const float*)d_in[7];
  const float* Bi   = (const float*)d_in[8];
  const float* Cr   = (const float*)d_in[9];
  const float* Ci   = (const float*)d_in[10];
  const float* stp  = (const float*)d_in[11];
  const float* Dp   = (const float*)d_in[12];
  const float* Wfc  = (const float*)d_in[13];
  const float* bfc  = (const float*)d_in[14];
  const float* lng  = (const float*)d_in[15];
  const float* lnb  = (const float*)d_in[16];

  char* ws = (char*)d_ws;
  float*    xT   = (float*)(ws);                                     // 32 MB
  float4*   S0   = (float4*)(ws + ((size_t)32 << 20));               // ~4.0 MB
  float4*   Tt   = (float4*)(ws + ((size_t)36 << 20) + (512u << 10));// 4 MB
  cf*       A    = (cf*)(ws + ((size_t)41 << 20));                   // 8 MB (dead after k_kf/k_s0)
  ushort*   y1h  = (ushort*)(ws + ((size_t)41 << 20));               // 16 MB (overlays A)
  ushort*   y1l  = (ushort*)(ws + ((size_t)57 << 20));               // 16 MB
  ushort*   Wh   = (ushort*)(ws + ((size_t)73 << 20));               // 128 KB
  ushort*   Wl   = (ushort*)(ws + ((size_t)73 << 20) + (128u << 10));
  unsigned* xmax = (unsigned*)(ws + ((size_t)73 << 20) + (256u << 10));
  unsigned* ymax = xmax + 2048;

  k_init<<<8, 256, 0, stream>>>(xmax, ymax);
  dim3 gt(64, 4, 8);
  k_transpose_x<<<gt, 256, 0, stream>>>(x, xT, xmax);
  k_wsplit<<<256, 256, 0, stream>>>(Wfc, Wh, Wl);
  k_cauchy<<<256, 256, 0, stream>>>(Lr, Li, Pr, Pi, Qr, Qi, Br, Bi, Cr, Ci, stp, A);
  k_s0<<<dim3(128, 9), 256, 0, stream>>>(A, S0);
  k_kf<<<128, 256, 32768, stream>>>(A, Tt);
  k_conv<<<1024, 256, 0, stream>>>(xT, S0, Tt, Dp, y1h, y1l);
  k_gemm_ln<<<512, 256, 0, stream>>>(y1h, y1l, Wh, Wl, bfc, x, lng, lnb, (float*)d_out, ymax);
  k_ratio<<<8, 256, 0, stream>>>(ymax, xmax, (float*)d_out);
}

// Round 7
// 222.149 us; speedup vs baseline: 1.6898x; 1.1315x over previous
//
#include <hip/hip_runtime.h>
#include <math.h>

#define TPB 256

typedef float2 cf;
typedef __attribute__((ext_vector_type(8))) short bf16x8;
typedef __attribute__((ext_vector_type(4))) float f32x4;

__device__ __forceinline__ cf cmk(float x, float y){ cf r; r.x=x; r.y=y; return r; }
__device__ __forceinline__ cf cml(cf a, cf b){ return cmk(a.x*b.x - a.y*b.y, a.x*b.y + a.y*b.x); }
__device__ __forceinline__ cf cad(cf a, cf b){ return cmk(a.x+b.x, a.y+b.y); }
__device__ __forceinline__ cf csb(cf a, cf b){ return cmk(a.x-b.x, a.y-b.y); }
__device__ __forceinline__ cf cjg(cf a){ return cmk(a.x, -a.y); }
__device__ __forceinline__ cf crcp(cf d){ float r = 1.0f/(d.x*d.x + d.y*d.y); return cmk(d.x*r, -d.y*r); }
__device__ __forceinline__ cf cdv(cf n, cf d){ return cml(n, crcp(d)); }
__device__ __forceinline__ float geluf(float z){ return 0.5f*z*(1.0f + erff(z*0.70710678118654752f)); }

// exp(sign*i*pi*f) via native v_sin/v_cos (input in revolutions)
__device__ __forceinline__ cf twid(float f, float sign){
  float h = f * 0.5f;
  float s = __builtin_amdgcn_sinf(h);
  float c0 = __builtin_amdgcn_cosf(h);
  return cmk(c0, sign * s);
}

__device__ __forceinline__ cf shflx(cf v, int m){
  return cmk(__shfl_xor(v.x, m), __shfl_xor(v.y, m));
}

__device__ __forceinline__ void bfsplit(float v, ushort* h, ushort* l){
  unsigned u = __float_as_uint(v);
  unsigned hr = (u + 0x7FFFu + ((u >> 16) & 1u)) & 0xFFFF0000u;
  *h = (ushort)(hr >> 16);
  float lv = v - __uint_as_float(hr);
  unsigned u2 = __float_as_uint(lv);
  *l = (ushort)((u2 + 0x7FFFu + ((u2 >> 16) & 1u)) >> 16);
}

// radix-4 butterflies on a register quad (strides 0,s,2s,3s), w1 = W(j, 4s)
__device__ __forceinline__ void dif4q(cf& q0, cf& q1, cf& q2, cf& q3, cf w1, float sign){
  cf w2 = cml(w1, w1);
  cf a1 = cad(q0, q2);
  cf c1 = cml(csb(q0, q2), w1);
  cf b1 = cad(q1, q3);
  cf d1 = cml(csb(q1, q3), cmk(-sign*w1.y, sign*w1.x));
  q0 = cad(a1, b1);
  q1 = cml(csb(a1, b1), w2);
  q2 = cad(c1, d1);
  q3 = cml(csb(c1, d1), w2);
}
__device__ __forceinline__ void dit4q(cf& q0, cf& q1, cf& q2, cf& q3, cf w1, float sign){
  cf w2 = cml(w1, w1);
  cf t1 = cml(q1, w2);
  cf a1 = cad(q0, t1), b1 = csb(q0, t1);
  cf t2 = cml(q3, w2);
  cf c1 = cad(q2, t2), d1 = csb(q2, t2);
  cf v1 = cml(c1, w1);
  cf v2 = cml(d1, cmk(-sign*w1.y, sign*w1.x));
  q0 = cad(a1, v1);
  q2 = csb(a1, v1);
  q1 = cad(b1, v2);
  q3 = csb(b1, v2);
}

// ---------------- legacy LDS FFT templates (used by k_kf, N=4096) ----------------
template<int N, int SSTART>
__device__ void fft_dif_r4(cf* __restrict__ a, float sign){
  #pragma unroll
  for (int s = SSTART; s >= 1; s >>= 2){
    __syncthreads();
    #pragma unroll
    for (int g = 0; g < (N >> 2) / TPB; g++){
      int w = (int)threadIdx.x + g * TPB;
      int j = w & (s - 1);
      int base = ((w & ~(s - 1)) << 2) | j;
      cf A0 = a[base], B0 = a[base + s], C0 = a[base + 2*s], D0 = a[base + 3*s];
      cf w1 = twid((float)j / (float)(2 * s), sign);
      cf w2 = cml(w1, w1);
      cf a1 = cad(A0, C0);
      cf c1 = cml(csb(A0, C0), w1);
      cf b1 = cad(B0, D0);
      cf d1 = cml(csb(B0, D0), cmk(-sign * w1.y, sign * w1.x));
      a[base]         = cad(a1, b1);
      a[base + s]     = cml(csb(a1, b1), w2);
      a[base + 2*s]   = cad(c1, d1);
      a[base + 3*s]   = cml(csb(c1, d1), w2);
    }
  }
  if constexpr ((__builtin_ctz(N) & 1) == 1){
    __syncthreads();
    #pragma unroll
    for (int g = 0; g < (N >> 1) / TPB; g++){
      int w = (int)threadIdx.x + g * TPB;
      int i = w << 1;
      cf u = a[i], v = a[i + 1];
      a[i] = cad(u, v);
      a[i + 1] = csb(u, v);
    }
  }
  __syncthreads();
}

template<int N>
__device__ void fft_dit_r4(cf* __restrict__ a, float sign){
  if constexpr ((__builtin_ctz(N) & 1) == 1){
    __syncthreads();
    #pragma unroll
    for (int g = 0; g < (N >> 1) / TPB; g++){
      int w = (int)threadIdx.x + g * TPB;
      int i = w << 1;
      cf u = a[i], v = a[i + 1];
      a[i] = cad(u, v);
      a[i + 1] = csb(u, v);
    }
  }
  constexpr int S0 = ((__builtin_ctz(N) & 1) == 1) ? 2 : 1;
  #pragma unroll
  for (int s = S0; s <= (N >> 2); s <<= 2){
    __syncthreads();
    #pragma unroll
    for (int g = 0; g < (N >> 2) / TPB; g++){
      int w = (int)threadIdx.x + g * TPB;
      int j = w & (s - 1);
      int base = ((w & ~(s - 1)) << 2) | j;
      cf A0 = a[base], B0 = a[base + s], C0 = a[base + 2*s], D0 = a[base + 3*s];
      cf w1 = twid((float)j / (float)(2 * s), sign);
      cf w2 = cml(w1, w1);
      cf t1 = cml(B0, w2);
      cf a1 = cad(A0, t1), b1 = csb(A0, t1);
      cf t2 = cml(D0, w2);
      cf c1 = cad(C0, t2), d1 = csb(C0, t2);
      cf v1 = cml(c1, w1);
      cf v2 = cml(d1, cmk(-sign * w1.y, sign * w1.x));
      a[base]         = cad(a1, v1);
      a[base + 2*s]   = csb(a1, v1);
      a[base + s]     = cad(b1, v2);
      a[base + 3*s]   = csb(b1, v2);
    }
  }
  __syncthreads();
}

__device__ __forceinline__ int brev12(int x){ return (int)(__brev((unsigned)x) >> 20); }

// ---------------- register FFT4096, 512 threads, 8 cf/thread ----------------
// M0: n = t + 512r (r=0..7) ; M1: n = a*512 + 64u + c (a=t>>6, c=t&63, u=0..7)
// LDS slot idx(n) = n + 4*(n>>8); buffer 4160 cf (33,280 B)
// DIF stage order: bits [11,10] [9] | T1 | [8,7] [6] | shuffles [5..0]

__device__ __forceinline__ void dif4096_reg(cf (&v)[8], cf* __restrict__ cb, int t){
  int a = t >> 6, cl = t & 63;
  #pragma unroll
  for (int r0 = 0; r0 < 2; r0++){
    cf w1 = twid((float)(t + 512*r0) * (1.0f/2048.0f), -1.0f);
    dif4q(v[r0], v[r0+2], v[r0+4], v[r0+6], w1, -1.0f);
  }
  {
    cf tw = twid((float)t * (1.0f/512.0f), -1.0f);
    #pragma unroll
    for (int r = 0; r < 8; r += 2){
      cf lo = cad(v[r], v[r+1]);
      cf hi = cml(csb(v[r], v[r+1]), tw);
      v[r] = lo; v[r+1] = hi;
    }
  }
  // T1
  __syncthreads();
  #pragma unroll
  for (int r = 0; r < 8; r++){ int n = t + 512*r; cb[n + 4*(n>>8)] = v[r]; }
  __syncthreads();
  #pragma unroll
  for (int u = 0; u < 8; u++){ int n = a*512 + 64*u + cl; v[u] = cb[n + 4*(n>>8)]; }
  #pragma unroll
  for (int u0 = 0; u0 < 2; u0++){
    cf w1 = twid((float)(64*u0 + cl) * (1.0f/256.0f), -1.0f);
    dif4q(v[u0], v[u0+2], v[u0+4], v[u0+6], w1, -1.0f);
  }
  {
    cf tw = twid((float)cl * (1.0f/64.0f), -1.0f);
    #pragma unroll
    for (int u = 0; u < 8; u += 2){
      cf lo = cad(v[u], v[u+1]);
      cf hi = cml(csb(v[u], v[u+1]), tw);
      v[u] = lo; v[u+1] = hi;
    }
  }
  // bits 5..0 via shuffles
  #pragma unroll
  for (int m = 32; m >= 2; m >>= 1){
    bool hb = (cl & m) != 0;
    cf tw = twid((float)(cl & (m-1)) * (1.0f/(float)m), -1.0f);
    #pragma unroll
    for (int u = 0; u < 8; u++){
      cf o = shflx(v[u], m);
      v[u] = hb ? cml(csb(o, v[u]), tw) : cad(v[u], o);
    }
  }
  {
    bool hb = (cl & 1) != 0;
    #pragma unroll
    for (int u = 0; u < 8; u++){
      cf o = shflx(v[u], 1);
      v[u] = hb ? csb(o, v[u]) : cad(v[u], o);
    }
  }
  // write M1 for pointwise
  #pragma unroll
  for (int u = 0; u < 8; u++){ int n = a*512 + 64*u + cl; cb[n + 4*(n>>8)] = v[u]; }
  __syncthreads();
}

__device__ __forceinline__ void dit4096_reg(cf (&v)[8], cf* __restrict__ cb, int t){
  int a = t >> 6, cl = t & 63;
  #pragma unroll
  for (int u = 0; u < 8; u++){ int n = a*512 + 64*u + cl; v[u] = cb[n + 4*(n>>8)]; }
  // bits 0..5 via shuffles
  {
    bool hb = (cl & 1) != 0;
    #pragma unroll
    for (int u = 0; u < 8; u++){
      cf o = shflx(v[u], 1);
      v[u] = hb ? csb(o, v[u]) : cad(v[u], o);
    }
  }
  #pragma unroll
  for (int m = 2; m <= 32; m <<= 1){
    bool hb = (cl & m) != 0;
    cf w = twid((float)(cl & (m-1)) * (1.0f/(float)m), 1.0f);
    #pragma unroll
    for (int u = 0; u < 8; u++){
      cf o = shflx(v[u], m);
      cf whv = cml(w, hb ? v[u] : o);
      v[u] = hb ? csb(o, whv) : cad(v[u], whv);
    }
  }
  // bit 6
  {
    cf tw = twid((float)cl * (1.0f/64.0f), 1.0f);
    #pragma unroll
    for (int u = 0; u < 8; u += 2){
      cf tb = cml(v[u+1], tw);
      cf a0 = v[u];
      v[u] = cad(a0, tb);
      v[u+1] = csb(a0, tb);
    }
  }
  // bits 7,8
  #pragma unroll
  for (int u0 = 0; u0 < 2; u0++){
    cf w1 = twid((float)(64*u0 + cl) * (1.0f/256.0f), 1.0f);
    dit4q(v[u0], v[u0+2], v[u0+4], v[u0+6], w1, 1.0f);
  }
  // T1'
  #pragma unroll
  for (int u = 0; u < 8; u++){ int n = a*512 + 64*u + cl; cb[n + 4*(n>>8)] = v[u]; }
  __syncthreads();
  #pragma unroll
  for (int r = 0; r < 8; r++){ int n = t + 512*r; v[r] = cb[n + 4*(n>>8)]; }
  // bit 9
  {
    cf tw = twid((float)t * (1.0f/512.0f), 1.0f);
    #pragma unroll
    for (int r = 0; r < 8; r += 2){
      cf tb = cml(v[r+1], tw);
      cf a0 = v[r];
      v[r] = cad(a0, tb);
      v[r+1] = csb(a0, tb);
    }
  }
  // bits 10,11
  #pragma unroll
  for (int r0 = 0; r0 < 2; r0++){
    cf w1 = twid((float)(t + 512*r0) * (1.0f/2048.0f), 1.0f);
    dit4q(v[r0], v[r0+2], v[r0+4], v[r0+6], w1, 1.0f);
  }
}

// ---------------- init atomic-max buffers ----------------
__global__ void k_init(unsigned* xmax, unsigned* ymax){
  int i = blockIdx.x * 256 + threadIdx.x;
  if (i < 2048){ xmax[i] = 0u; ymax[i] = 0u; }
}

// ---------------- transpose x (B,L,H)->(B,H,L), fused max|x| ----------------
__global__ __launch_bounds__(256) void k_transpose_x(const float* __restrict__ x,
                                                     float* __restrict__ xT,
                                                     unsigned* __restrict__ xmax){
  __shared__ float tile[64][65];
  __shared__ float red[64][4];
  int b = blockIdx.z;
  int t0 = blockIdx.x * 64;
  int h0 = blockIdx.y * 64;
  int hc = threadIdx.x & 63, tg = threadIdx.x >> 6;
  float pmax = 0.0f;
  #pragma unroll
  for (int q = 0; q < 16; q++){
    int tr = tg + q * 4;
    float v = x[((size_t)(b * 4096 + t0 + tr)) * 256 + h0 + hc];
    tile[tr][hc] = v;
    pmax = fmaxf(pmax, fabsf(v));
  }
  red[hc][tg] = pmax;
  __syncthreads();
  if (threadIdx.x < 64){
    float m = fmaxf(fmaxf(red[threadIdx.x][0], red[threadIdx.x][1]),
                    fmaxf(red[threadIdx.x][2], red[threadIdx.x][3]));
    atomicMax(&xmax[b * 256 + h0 + threadIdx.x], __float_as_uint(m));
  }
  #pragma unroll
  for (int q = 0; q < 16; q++){
    int hr = tg + q * 4;
    xT[((size_t)(b * 256 + h0 + hr)) * 4096 + t0 + hc] = tile[hc][hr];
  }
}

// ---------------- W -> bf16 hi/lo planes ----------------
__global__ void k_wsplit(const float* __restrict__ W, ushort* __restrict__ Wh, ushort* __restrict__ Wl){
  int i = blockIdx.x * 256 + threadIdx.x;
  ushort h, l;
  bfsplit(W[i], &h, &l);
  Wh[i] = h; Wl[i] = l;
}

// ---------------- Cauchy / generating function ----------------
__global__ __launch_bounds__(256) void k_cauchy(
    const float* __restrict__ Lr, const float* __restrict__ Li,
    const float* __restrict__ Pr, const float* __restrict__ Pi,
    const float* __restrict__ Qr, const float* __restrict__ Qi,
    const float* __restrict__ Br, const float* __restrict__ Bi,
    const float* __restrict__ Cr, const float* __restrict__ Ci,
    const float* __restrict__ stepp, cf* __restrict__ A)
{
  __shared__ cf sLam[64], sB[64], sP[64], sQB[64], sQP[64];
  __shared__ cf sInv[64][16];
  __shared__ cf sWood[16], sC[16], sG[16];
  int tid = threadIdx.x;
  int l0 = blockIdx.x * 16;
  float stepv = fmaxf(stepp[0], 1e-6f);
  if (tid < 64){
    cf lam = cmk(Lr[tid], Li[tid]);
    cf b = cmk(Br[tid], Bi[tid]);
    cf p = cmk(Pr[tid], Pi[tid]);
    cf q = cmk(Qr[tid], Qi[tid]);
    sLam[tid] = lam; sB[tid] = b; sP[tid] = p;
    sQB[tid] = cml(q, b);
    sQP[tid] = cml(q, p);
  }
  __syncthreads();
  if (tid < 16){
    int l = l0 + tid;
    float ang = -6.2831855f * ((float)l * (1.0f / 4096.0f));
    cf Om = cmk(cosf(ang), sinf(ang));
    cf den = cmk(1.0f + Om.x, Om.y);
    cf num = cmk(1.0f - Om.x, -Om.y);
    cf rden = crcp(den);
    sC[tid] = cml(cmk(2.0f, 0.0f), rden);
    cf g = cml(num, rden);
    float sc = 2.0f / stepv;
    sG[tid] = cmk(g.x * sc, g.y * sc);
  }
  __syncthreads();
  for (int it = tid; it < 1024; it += 256){
    int n = it >> 4, ll = it & 15;
    sInv[n][ll] = crcp(csb(sG[ll], sLam[n]));
  }
  __syncthreads();
  if (tid < 16){
    cf k10 = cmk(0,0), k11 = cmk(0,0);
    for (int n = 0; n < 64; n++){
      k10 = cad(k10, cml(sQB[n], sInv[n][tid]));
      k11 = cad(k11, cml(sQP[n], sInv[n][tid]));
    }
    sWood[tid] = cdv(k10, cmk(1.0f + k11.x, k11.y));
  }
  __syncthreads();
  int h = tid;
  cf a0[16], a1[16];
  #pragma unroll
  for (int ll = 0; ll < 16; ll++){ a0[ll] = cmk(0,0); a1[ll] = cmk(0,0); }
  for (int n = 0; n < 64; n++){
    cf cc = cmk(Cr[h * 64 + n], Ci[h * 64 + n]);
    cf cb = cml(cc, sB[n]);
    cf cp = cml(cc, sP[n]);
    #pragma unroll
    for (int ll = 0; ll < 16; ll++){
      cf iv = sInv[n][ll];
      a0[ll] = cad(a0[ll], cml(cb, iv));
      a1[ll] = cad(a1[ll], cml(cp, iv));
    }
  }
  cf* dst = A + (size_t)h * 4096 + l0;
  #pragma unroll
  for (int ll = 0; ll < 16; ll++){
    dst[ll] = cml(sC[ll], csb(a0[ll], cml(a1[ll], sWood[ll])));
  }
}

// ---------------- S0 table (circular pass): Sa/Sb from symmetrized A, bitrev-paired ----------------
__global__ __launch_bounds__(256) void k_s0(const cf* __restrict__ A, float4* __restrict__ S0){
  int hp = blockIdx.x;
  int rec = blockIdx.y * 256 + threadIdx.x;
  if (rec > 2048) return;
  int k = (rec < 2048) ? brev12(rec << 1) : 2048;
  int mk = (4096 - k) & 4095;
  const cf* a1p = A + (size_t)(2 * hp) * 4096;
  const cf* a2p = a1p + 4096;
  cf K1 = cad(a1p[k], cjg(a1p[mk]));   // 2*K1f[k]
  cf K2 = cad(a2p[k], cjg(a2p[mk]));
  const float s = 1.0f / 32768.0f;
  S0[(size_t)hp * 2049 + rec] = make_float4((K1.x + K2.x) * s, (K1.y + K2.y) * s,
                                            (K1.x - K2.x) * s, (K1.y - K2.y) * s);
}

// ---------------- T table (negacyclic pass): DIT4096(A) -> twist -> DIF4096 -> pair-unpack ----------------
__global__ __launch_bounds__(256) void k_kf(const cf* __restrict__ A, float4* __restrict__ Tt){
  extern __shared__ cf c[];    // 4096 cf
  int hp = blockIdx.x, tid = threadIdx.x;
  const cf* a1p = A + (size_t)(2 * hp) * 4096;
  const cf* a2p = a1p + 4096;
  for (int l = tid; l < 4096; l += TPB){
    int r = brev12(l);
    cf u = a1p[l], w = a2p[l];
    c[r] = cmk(u.x - w.y, u.y + w.x);          // A1 + i*A2, bitrev order
  }
  fft_dit_r4<4096>(c, 1.0f);                   // -> 4096*(k1 + i*k2), natural
  const float inv = 1.0f / 4096.0f;
  for (int l = tid; l < 4096; l += TPB){
    cf tw = twid((float)l * inv, -1.0f);       // tau[l]
    tw.x *= inv; tw.y *= inv;
    c[l] = cml(c[l], tw);
  }
  fft_dif_r4<4096, 1024>(c, -1.0f);            // Z = FFT(K~ * tau), bitrev order
  float4* rec = Tt + (size_t)hp * 2048;
  const float st = 1.0f / 32768.0f;
  #pragma unroll
  for (int q8 = 0; q8 < 8; q8++){
    int tr = tid + 256 * q8;
    int p = tr << 1;
    int k = brev12(p);
    int qs = brev12(4095 - k);
    cf Zp = c[p], Zq = c[qs];
    float G1x = Zp.x + Zq.x, G1y = Zp.y - Zq.y;
    float dx = Zp.x - Zq.x, dy = Zp.y + Zq.y;
    float G2x = dy, G2y = -dx;
    rec[tr] = make_float4((G1x + G2x) * st, (G1y + G2y) * st,
                          (G1x - G2x) * st, (G1y - G2y) * st);
  }
}

// ---------------- conv: circular+negacyclic 4096 register FFTs, 512 threads, 2 ch/block ----------------
__global__ __launch_bounds__(512) void k_conv(const float* __restrict__ xT,
                                              const float4* __restrict__ S0,
                                              const float4* __restrict__ Tt,
                                              const float* __restrict__ Dp,
                                              ushort* __restrict__ y1h,
                                              ushort* __restrict__ y1l){
  __shared__ cf cb[4160];
  int blk = blockIdx.x;
  int b = blk >> 7, hp = blk & 127;
  int t = threadIdx.x;
  const float* xs1 = xT + ((size_t)(b * 256 + 2 * hp)) * 4096;
  const float* xs2 = xs1 + 4096;
  cf v[8];
  #pragma unroll
  for (int r = 0; r < 8; r++){
    int n = t + 512 * r;
    v[r] = cmk(xs1[n], xs2[n]);
  }
  // ---- pass 0: circular ----
  dif4096_reg(v, cb, t);
  {
    const float4* rec0 = S0 + (size_t)hp * 2049;
    #pragma unroll
    for (int q8 = 0; q8 < 4; q8++){
      int tr = t + 512 * q8;
      int p = tr << 1;
      int k = brev12(p);
      int q0 = brev12((4096 - k) & 4095);
      int pi = p + 4 * (p >> 8), qi = q0 + 4 * (q0 >> 8);
      cf Zp = cb[pi], Zq = cb[qi];
      float4 r0 = rec0[tr];
      cf Sa = cmk(r0.x, r0.y), Sb = cmk(r0.z, r0.w);
      cb[pi] = cad(cml(Zp, Sa), cml(cjg(Zq), Sb));
      cb[qi] = cad(cml(Zq, cjg(Sa)), cml(cjg(Zp), cjg(Sb)));
    }
    if (t == 0){
      float4 e = rec0[2048];
      cf Z1 = cb[1];
      cb[1] = cad(cml(Z1, cmk(e.x, e.y)), cml(cjg(Z1), cmk(e.z, e.w)));
    }
  }
  __syncthreads();
  dit4096_reg(v, cb, t);
  cf acc[8];
  #pragma unroll
  for (int r = 0; r < 8; r++) acc[r] = v[r];
  // ---- pass 1: negacyclic (reload x + pre-twist) ----
  #pragma unroll
  for (int r = 0; r < 8; r++){
    int n = t + 512 * r;
    cf xv = cmk(xs1[n], xs2[n]);
    v[r] = cml(xv, twid((float)n * (1.0f / 4096.0f), -1.0f));
  }
  dif4096_reg(v, cb, t);
  {
    const float4* rec1 = Tt + (size_t)hp * 2048;
    #pragma unroll
    for (int q8 = 0; q8 < 4; q8++){
      int tr = t + 512 * q8;
      int p = tr << 1;
      int k = brev12(p);
      int q1 = brev12(4095 - k);
      int pi = p + 4 * (p >> 8), qi = q1 + 4 * (q1 >> 8);
      cf Zp = cb[pi], Zq = cb[qi];
      float4 r0 = rec1[tr];
      cf Ta = cmk(r0.x, r0.y), Tb = cmk(r0.z, r0.w);
      cb[pi] = cad(cml(Zp, Ta), cml(cjg(Zq), Tb));
      cb[qi] = cad(cml(Zq, cjg(Ta)), cml(cjg(Zp), cjg(Tb)));
    }
  }
  __syncthreads();
  dit4096_reg(v, cb, t);
  // ---- combine (post-twist pass1) + epilogue (reload x) ----
  float Dv = Dp[0];
  size_t base = ((size_t)(b * 256 + 2 * hp)) * 4096;
  #pragma unroll
  for (int r = 0; r < 8; r++){
    int n = t + 512 * r;
    cf u = cml(v[r], twid((float)n * (1.0f / 4096.0f), 1.0f));  // conj(tau)
    float y1 = acc[r].x + u.x;
    float y2 = acc[r].y + u.y;
    float z1 = geluf(fmaf(Dv, xs1[n], y1));
    float z2 = geluf(fmaf(Dv, xs2[n], y2));
    ushort h0, l0, h1u, l1;
    bfsplit(z1, &h0, &l0);
    bfsplit(z2, &h1u, &l1);
    y1h[base + n] = h0;         y1l[base + n] = l0;
    y1h[base + 4096 + n] = h1u; y1l[base + 4096 + n] = l1;
  }
}

// ---------------- MFMA split-bf16 GEMM + gelu + skip + LayerNorm + max|y| ----------------
__global__ __launch_bounds__(256, 3) void k_gemm_ln(
    const ushort* __restrict__ y1h, const ushort* __restrict__ y1l,
    const ushort* __restrict__ Wh, const ushort* __restrict__ Wl,
    const float* __restrict__ bfc, const float* __restrict__ x,
    const float* __restrict__ lng, const float* __restrict__ lnb,
    float* __restrict__ yout, unsigned* __restrict__ ymax)
{
  __shared__ ushort sY[2][64 * 40];
  __shared__ float red1[64][4], red2[64][4];
  int tid = threadIdx.x;
  int l = tid & 63;
  int w = tid >> 6;
  int blk = blockIdx.x;
  int b = blk >> 6;
  int t0 = (blk & 63) * 64;
  int g = l >> 4, cc = l & 15;

  f32x4 acc[4][4];
  #pragma unroll
  for (int m = 0; m < 4; m++)
    #pragma unroll
    for (int n = 0; n < 4; n++)
      acc[m][n] = (f32x4){0.0f, 0.0f, 0.0f, 0.0f};

  int kk = tid >> 3, ts = (tid & 7) * 8;

  #pragma unroll 1
  for (int kc = 0; kc < 256; kc += 32){
    __syncthreads();
    {
      size_t gb = ((size_t)(b * 256 + kc + kk)) * 4096 + t0 + ts;
      float4 vh = *(const float4*)(y1h + gb);
      float4 vl = *(const float4*)(y1l + gb);
      const ushort* ph = (const ushort*)&vh;
      const ushort* pl = (const ushort*)&vl;
      int kblk = kk >> 3, kin = kk & 7;
      #pragma unroll
      for (int e = 0; e < 8; e++){
        int t = ts + e;
        int idx = t * 40 + ((kblk ^ ((t >> 3) & 3)) << 3) + kin;
        sY[0][idx] = ph[e];
        sY[1][idx] = pl[e];
      }
    }
    __syncthreads();
    bf16x8 afh[4], afl[4];
    #pragma unroll
    for (int m = 0; m < 4; m++){
      int t = m * 16 + cc;
      int idx = t * 40 + ((g ^ ((t >> 3) & 3)) << 3);
      afh[m] = *(bf16x8*)&sY[0][idx];
      afl[m] = *(bf16x8*)&sY[1][idx];
    }
    #pragma unroll
    for (int n = 0; n < 4; n++){
      size_t wj = (size_t)(w * 64 + n * 16 + cc) * 256 + kc + g * 8;
      bf16x8 bh = *(const bf16x8*)(Wh + wj);
      bf16x8 bl = *(const bf16x8*)(Wl + wj);
      #pragma unroll
      for (int m = 0; m < 4; m++){
        acc[m][n] = __builtin_amdgcn_mfma_f32_16x16x32_bf16(afh[m], bh, acc[m][n], 0, 0, 0);
        acc[m][n] = __builtin_amdgcn_mfma_f32_16x16x32_bf16(afh[m], bl, acc[m][n], 0, 0, 0);
        acc[m][n] = __builtin_amdgcn_mfma_f32_16x16x32_bf16(afl[m], bh, acc[m][n], 0, 0, 0);
      }
    }
  }

  float bj[4], gj[4], lj[4];
  #pragma unroll
  for (int n = 0; n < 4; n++){
    int j = w * 64 + n * 16 + cc;
    bj[n] = bfc[j]; gj[n] = lng[j]; lj[n] = lnb[j];
  }
  #pragma unroll
  for (int m = 0; m < 4; m++){
    #pragma unroll
    for (int r = 0; r < 4; r++){
      int tl = m * 16 + g * 4 + r;
      size_t rowb = ((size_t)(b * 4096 + t0 + tl)) * 256;
      float ss = 0.0f, sq = 0.0f;
      #pragma unroll
      for (int n = 0; n < 4; n++){
        float z = geluf(acc[m][n][r] + bj[n]) + x[rowb + w * 64 + n * 16 + cc];
        acc[m][n][r] = z;
        ss += z; sq = fmaf(z, z, sq);
      }
      #pragma unroll
      for (int msk = 1; msk < 16; msk <<= 1){
        ss += __shfl_xor(ss, msk);
        sq += __shfl_xor(sq, msk);
      }
      if (cc == 0){ red1[tl][w] = ss; red2[tl][w] = sq; }
    }
  }
  __syncthreads();
  float jm[4] = {0.0f, 0.0f, 0.0f, 0.0f};
  #pragma unroll
  for (int m = 0; m < 4; m++){
    #pragma unroll
    for (int r = 0; r < 4; r++){
      int tl = m * 16 + g * 4 + r;
      float ts1 = red1[tl][0] + red1[tl][1] + red1[tl][2] + red1[tl][3];
      float ts2 = red2[tl][0] + red2[tl][1] + red2[tl][2] + red2[tl][3];
      float mu = ts1 * (1.0f / 256.0f);
      float var = ts2 * (1.0f / 256.0f) - mu * mu;
      float rstd = rsqrtf(var + 1e-5f);
      size_t rowb = ((size_t)(b * 4096 + t0 + tl)) * 256;
      #pragma unroll
      for (int n = 0; n < 4; n++){
        float yv = (acc[m][n][r] - mu) * rstd * gj[n] + lj[n];
        yout[rowb + w * 64 + n * 16 + cc] = yv;
        jm[n] = fmaxf(jm[n], fabsf(yv));
      }
    }
  }
  #pragma unroll
  for (int n = 0; n < 4; n++){
    jm[n] = fmaxf(jm[n], __shfl_xor(jm[n], 16));
    jm[n] = fmaxf(jm[n], __shfl_xor(jm[n], 32));
  }
  if (g == 0){
    #pragma unroll
    for (int n = 0; n < 4; n++)
      atomicMax(&ymax[b * 256 + w * 64 + n * 16 + cc], __float_as_uint(jm[n]));
  }
}

// ---------------- final ratio ----------------
__global__ void k_ratio(const unsigned* __restrict__ ymax, const unsigned* __restrict__ xmax,
                        float* __restrict__ out){
  int i = blockIdx.x * 256 + threadIdx.x;
  if (i < 2048){
    float ym = __uint_as_float(ymax[i]);
    float xm = __uint_as_float(xmax[i]);
    out[8388608 + i] = ym / (xm + 1e-6f);
  }
}

extern "C" void kernel_launch(void* const* d_in, const int* in_sizes, int n_in,
                              void* d_out, int out_size, void* d_ws, size_t ws_size,
                              hipStream_t stream)
{
  const float* x    = (const float*)d_in[0];
  const float* Lr   = (const float*)d_in[1];
  const float* Li   = (const float*)d_in[2];
  const float* Pr   = (const float*)d_in[3];
  const float* Pi   = (const float*)d_in[4];
  const float* Qr   = (const float*)d_in[5];
  const float* Qi   = (const float*)d_in[6];
  const float* Br   = (const float*)d_in[7];
  const float* Bi   = (const float*)d_in[8];
  const float* Cr   = (const float*)d_in[9];
  const float* Ci   = (const float*)d_in[10];
  const float* stp  = (const float*)d_in[11];
  const float* Dp   = (const float*)d_in[12];
  const float* Wfc  = (const float*)d_in[13];
  const float* bfc  = (const float*)d_in[14];
  const float* lng  = (const float*)d_in[15];
  const float* lnb  = (const float*)d_in[16];

  char* ws = (char*)d_ws;
  float*    xT   = (float*)(ws);                                     // 32 MB
  float4*   S0   = (float4*)(ws + ((size_t)32 << 20));               // ~4.0 MB
  float4*   Tt   = (float4*)(ws + ((size_t)36 << 20) + (512u << 10));// 4 MB
  cf*       A    = (cf*)(ws + ((size_t)41 << 20));                   // 8 MB (dead after k_kf/k_s0)
  ushort*   y1h  = (ushort*)(ws + ((size_t)41 << 20));               // 16 MB (overlays A)
  ushort*   y1l  = (ushort*)(ws + ((size_t)57 << 20));               // 16 MB
  ushort*   Wh   = (ushort*)(ws + ((size_t)73 << 20));               // 128 KB
  ushort*   Wl   = (ushort*)(ws + ((size_t)73 << 20) + (128u << 10));
  unsigned* xmax = (unsigned*)(ws + ((size_t)73 << 20) + (256u << 10));
  unsigned* ymax = xmax + 2048;

  k_init<<<8, 256, 0, stream>>>(xmax, ymax);
  dim3 gt(64, 4, 8);
  k_transpose_x<<<gt, 256, 0, stream>>>(x, xT, xmax);
  k_wsplit<<<256, 256, 0, stream>>>(Wfc, Wh, Wl);
  k_cauchy<<<256, 256, 0, stream>>>(Lr, Li, Pr, Pi, Qr, Qi, Br, Bi, Cr, Ci, stp, A);
  k_s0<<<dim3(128, 9), 256, 0, stream>>>(A, S0);
  k_kf<<<128, 256, 32768, stream>>>(A, Tt);
  k_conv<<<1024, 512, 0, stream>>>(xT, S0, Tt, Dp, y1h, y1l);
  k_gemm_ln<<<512, 256, 0, stream>>>(y1h, y1l, Wh, Wl, bfc, x, lng, lnb, (float*)d_out, ymax);
  k_ratio<<<8, 256, 0, stream>>>(ymax, xmax, (float*)d_out);
}

// Round 8
// 215.040 us; speedup vs baseline: 1.7456x; 1.0331x over previous
//
#include <hip/hip_runtime.h>
#include <math.h>

typedef float2 cf;
typedef __attribute__((ext_vector_type(8))) short bf16x8;
typedef __attribute__((ext_vector_type(4))) float f32x4;

__device__ __forceinline__ cf cmk(float x, float y){ cf r; r.x=x; r.y=y; return r; }
__device__ __forceinline__ cf cml(cf a, cf b){ return cmk(a.x*b.x - a.y*b.y, a.x*b.y + a.y*b.x); }
__device__ __forceinline__ cf cad(cf a, cf b){ return cmk(a.x+b.x, a.y+b.y); }
__device__ __forceinline__ cf csb(cf a, cf b){ return cmk(a.x-b.x, a.y-b.y); }
__device__ __forceinline__ cf cjg(cf a){ return cmk(a.x, -a.y); }
__device__ __forceinline__ cf crcp(cf d){ float r = 1.0f/(d.x*d.x + d.y*d.y); return cmk(d.x*r, -d.y*r); }
__device__ __forceinline__ cf cdv(cf n, cf d){ return cml(n, crcp(d)); }
__device__ __forceinline__ float geluf(float z){ return 0.5f*z*(1.0f + erff(z*0.70710678118654752f)); }

// exp(sign*i*pi*f) via native v_sin/v_cos (input in revolutions)
__device__ __forceinline__ cf twid(float f, float sign){
  float h = f * 0.5f;
  float s = __builtin_amdgcn_sinf(h);
  float c0 = __builtin_amdgcn_cosf(h);
  return cmk(c0, sign * s);
}

__device__ __forceinline__ cf shflx(cf v, int m){
  return cmk(__shfl_xor(v.x, m), __shfl_xor(v.y, m));
}

__device__ __forceinline__ void bfsplit(float v, ushort* h, ushort* l){
  unsigned u = __float_as_uint(v);
  unsigned hr = (u + 0x7FFFu + ((u >> 16) & 1u)) & 0xFFFF0000u;
  *h = (ushort)(hr >> 16);
  float lv = v - __uint_as_float(hr);
  unsigned u2 = __float_as_uint(lv);
  *l = (ushort)((u2 + 0x7FFFu + ((u2 >> 16) & 1u)) >> 16);
}

// radix-4 butterflies on a register quad (strides 0,s,2s,3s), w1 = twid(j/(2s))
__device__ __forceinline__ void dif4q(cf& q0, cf& q1, cf& q2, cf& q3, cf w1, float sign){
  cf w2 = cml(w1, w1);
  cf a1 = cad(q0, q2);
  cf c1 = cml(csb(q0, q2), w1);
  cf b1 = cad(q1, q3);
  cf d1 = cml(csb(q1, q3), cmk(-sign*w1.y, sign*w1.x));
  q0 = cad(a1, b1);
  q1 = cml(csb(a1, b1), w2);
  q2 = cad(c1, d1);
  q3 = cml(csb(c1, d1), w2);
}
__device__ __forceinline__ void dit4q(cf& q0, cf& q1, cf& q2, cf& q3, cf w1, float sign){
  cf w2 = cml(w1, w1);
  cf t1 = cml(q1, w2);
  cf a1 = cad(q0, t1), b1 = csb(q0, t1);
  cf t2 = cml(q3, w2);
  cf c1 = cad(q2, t2), d1 = csb(q2, t2);
  cf v1 = cml(c1, w1);
  cf v2 = cml(d1, cmk(-sign*w1.y, sign*w1.x));
  q0 = cad(a1, v1);
  q2 = csb(a1, v1);
  q1 = cad(b1, v2);
  q3 = csb(b1, v2);
}

__device__ __forceinline__ int brev12(int x){ return (int)(__brev((unsigned)x) >> 20); }
__device__ __forceinline__ int pidx(int n){ return n + 4*(n>>8); }

// ---------------- register FFT4096, 1024 threads, 4 cf/thread ----------------
// M0: n = t + 1024r ; M1: n = (t>>8)*1024 + u*256 + (t&255) ; M2: n = (t>>6)*256 + u*64 + (t&63)
// LDS slots use pidx(); after dif: slot p holds bin brev12(p).

__device__ __forceinline__ void dif4096_reg4(cf (&v)[4], cf* __restrict__ cb, int t, float sign){
  // stage A: bits 11,10 (s=1024, j=t)
  {
    cf w1 = twid((float)t * (1.0f/2048.0f), sign);
    dif4q(v[0], v[1], v[2], v[3], w1, sign);
  }
  __syncthreads();
  #pragma unroll
  for (int r = 0; r < 4; r++) cb[pidx(t + 1024*r)] = v[r];
  __syncthreads();
  int a1 = t >> 8, c1 = t & 255;
  #pragma unroll
  for (int u = 0; u < 4; u++) v[u] = cb[pidx(a1*1024 + u*256 + c1)];
  // stage B: bits 9,8 (s=256, j=c1)
  {
    cf w1 = twid((float)c1 * (1.0f/512.0f), sign);
    dif4q(v[0], v[1], v[2], v[3], w1, sign);
  }
  #pragma unroll
  for (int u = 0; u < 4; u++) cb[pidx(a1*1024 + u*256 + c1)] = v[u];  // own slots
  __syncthreads();
  int a2 = t >> 6, c2 = t & 63;
  #pragma unroll
  for (int u = 0; u < 4; u++) v[u] = cb[pidx(a2*256 + u*64 + c2)];
  // stage C: bits 7,6 (s=64, j=c2)
  {
    cf w1 = twid((float)c2 * (1.0f/128.0f), sign);
    dif4q(v[0], v[1], v[2], v[3], w1, sign);
  }
  // bits 5..1 via shuffles (with twiddle), bit 0 plain
  #pragma unroll
  for (int m = 32; m >= 2; m >>= 1){
    bool hb = (c2 & m) != 0;
    cf tw = twid((float)(c2 & (m-1)) * (1.0f/(float)m), sign);
    #pragma unroll
    for (int u = 0; u < 4; u++){
      cf o = shflx(v[u], m);
      v[u] = hb ? cml(csb(o, v[u]), tw) : cad(v[u], o);
    }
  }
  {
    bool hb = (c2 & 1) != 0;
    #pragma unroll
    for (int u = 0; u < 4; u++){
      cf o = shflx(v[u], 1);
      v[u] = hb ? csb(o, v[u]) : cad(v[u], o);
    }
  }
  #pragma unroll
  for (int u = 0; u < 4; u++) cb[pidx(a2*256 + u*64 + c2)] = v[u];    // own slots
  __syncthreads();
}

__device__ __forceinline__ void dit4096_reg4(cf (&v)[4], cf* __restrict__ cb, int t, float sign){
  int a2 = t >> 6, c2 = t & 63;
  #pragma unroll
  for (int u = 0; u < 4; u++) v[u] = cb[pidx(a2*256 + u*64 + c2)];
  // bit 0 plain, bits 1..5 via shuffles
  {
    bool hb = (c2 & 1) != 0;
    #pragma unroll
    for (int u = 0; u < 4; u++){
      cf o = shflx(v[u], 1);
      v[u] = hb ? csb(o, v[u]) : cad(v[u], o);
    }
  }
  #pragma unroll
  for (int m = 2; m <= 32; m <<= 1){
    bool hb = (c2 & m) != 0;
    cf w = twid((float)(c2 & (m-1)) * (1.0f/(float)m), sign);
    #pragma unroll
    for (int u = 0; u < 4; u++){
      cf o = shflx(v[u], m);
      cf whv = cml(w, hb ? v[u] : o);
      v[u] = hb ? csb(o, whv) : cad(v[u], whv);
    }
  }
  // stage C': bits 7,6
  {
    cf w1 = twid((float)c2 * (1.0f/128.0f), sign);
    dit4q(v[0], v[1], v[2], v[3], w1, sign);
  }
  #pragma unroll
  for (int u = 0; u < 4; u++) cb[pidx(a2*256 + u*64 + c2)] = v[u];
  __syncthreads();
  int a1 = t >> 8, c1 = t & 255;
  #pragma unroll
  for (int u = 0; u < 4; u++) v[u] = cb[pidx(a1*1024 + u*256 + c1)];
  // stage B': bits 9,8
  {
    cf w1 = twid((float)c1 * (1.0f/512.0f), sign);
    dit4q(v[0], v[1], v[2], v[3], w1, sign);
  }
  #pragma unroll
  for (int u = 0; u < 4; u++) cb[pidx(a1*1024 + u*256 + c1)] = v[u];
  __syncthreads();
  #pragma unroll
  for (int r = 0; r < 4; r++) v[r] = cb[pidx(t + 1024*r)];
  // stage A': bits 11,10
  {
    cf w1 = twid((float)t * (1.0f/2048.0f), sign);
    dit4q(v[0], v[1], v[2], v[3], w1, sign);
  }
}

// ---------------- init atomic-max buffers ----------------
__global__ void k_init(unsigned* xmax, unsigned* ymax){
  int i = blockIdx.x * 256 + threadIdx.x;
  if (i < 2048){ xmax[i] = 0u; ymax[i] = 0u; }
}

// ---------------- transpose x (B,L,H)->(B,H,L), fused max|x| ----------------
__global__ __launch_bounds__(256) void k_transpose_x(const float* __restrict__ x,
                                                     float* __restrict__ xT,
                                                     unsigned* __restrict__ xmax){
  __shared__ float tile[64][65];
  __shared__ float red[64][4];
  int b = blockIdx.z;
  int t0 = blockIdx.x * 64;
  int h0 = blockIdx.y * 64;
  int hc = threadIdx.x & 63, tg = threadIdx.x >> 6;
  float pmax = 0.0f;
  #pragma unroll
  for (int q = 0; q < 16; q++){
    int tr = tg + q * 4;
    float v = x[((size_t)(b * 4096 + t0 + tr)) * 256 + h0 + hc];
    tile[tr][hc] = v;
    pmax = fmaxf(pmax, fabsf(v));
  }
  red[hc][tg] = pmax;
  __syncthreads();
  if (threadIdx.x < 64){
    float m = fmaxf(fmaxf(red[threadIdx.x][0], red[threadIdx.x][1]),
                    fmaxf(red[threadIdx.x][2], red[threadIdx.x][3]));
    atomicMax(&xmax[b * 256 + h0 + threadIdx.x], __float_as_uint(m));
  }
  #pragma unroll
  for (int q = 0; q < 16; q++){
    int hr = tg + q * 4;
    xT[((size_t)(b * 256 + h0 + hr)) * 4096 + t0 + hc] = tile[hc][hr];
  }
}

// ---------------- W -> bf16 hi/lo planes ----------------
__global__ void k_wsplit(const float* __restrict__ W, ushort* __restrict__ Wh, ushort* __restrict__ Wl){
  int i = blockIdx.x * 256 + threadIdx.x;
  ushort h, l;
  bfsplit(W[i], &h, &l);
  Wh[i] = h; Wl[i] = l;
}

// ---------------- Cauchy / generating function ----------------
__global__ __launch_bounds__(256) void k_cauchy(
    const float* __restrict__ Lr, const float* __restrict__ Li,
    const float* __restrict__ Pr, const float* __restrict__ Pi,
    const float* __restrict__ Qr, const float* __restrict__ Qi,
    const float* __restrict__ Br, const float* __restrict__ Bi,
    const float* __restrict__ Cr, const float* __restrict__ Ci,
    const float* __restrict__ stepp, cf* __restrict__ A)
{
  __shared__ cf sLam[64], sB[64], sP[64], sQB[64], sQP[64];
  __shared__ cf sInv[64][16];
  __shared__ cf sWood[16], sC[16], sG[16];
  int tid = threadIdx.x;
  int l0 = blockIdx.x * 16;
  float stepv = fmaxf(stepp[0], 1e-6f);
  if (tid < 64){
    cf lam = cmk(Lr[tid], Li[tid]);
    cf b = cmk(Br[tid], Bi[tid]);
    cf p = cmk(Pr[tid], Pi[tid]);
    cf q = cmk(Qr[tid], Qi[tid]);
    sLam[tid] = lam; sB[tid] = b; sP[tid] = p;
    sQB[tid] = cml(q, b);
    sQP[tid] = cml(q, p);
  }
  __syncthreads();
  if (tid < 16){
    int l = l0 + tid;
    float ang = -6.2831855f * ((float)l * (1.0f / 4096.0f));
    cf Om = cmk(cosf(ang), sinf(ang));
    cf den = cmk(1.0f + Om.x, Om.y);
    cf num = cmk(1.0f - Om.x, -Om.y);
    cf rden = crcp(den);
    sC[tid] = cml(cmk(2.0f, 0.0f), rden);
    cf g = cml(num, rden);
    float sc = 2.0f / stepv;
    sG[tid] = cmk(g.x * sc, g.y * sc);
  }
  __syncthreads();
  for (int it = tid; it < 1024; it += 256){
    int n = it >> 4, ll = it & 15;
    sInv[n][ll] = crcp(csb(sG[ll], sLam[n]));
  }
  __syncthreads();
  if (tid < 16){
    cf k10 = cmk(0,0), k11 = cmk(0,0);
    for (int n = 0; n < 64; n++){
      k10 = cad(k10, cml(sQB[n], sInv[n][tid]));
      k11 = cad(k11, cml(sQP[n], sInv[n][tid]));
    }
    sWood[tid] = cdv(k10, cmk(1.0f + k11.x, k11.y));
  }
  __syncthreads();
  int h = tid;
  cf a0[16], a1[16];
  #pragma unroll
  for (int ll = 0; ll < 16; ll++){ a0[ll] = cmk(0,0); a1[ll] = cmk(0,0); }
  for (int n = 0; n < 64; n++){
    cf cc = cmk(Cr[h * 64 + n], Ci[h * 64 + n]);
    cf cb = cml(cc, sB[n]);
    cf cp = cml(cc, sP[n]);
    #pragma unroll
    for (int ll = 0; ll < 16; ll++){
      cf iv = sInv[n][ll];
      a0[ll] = cad(a0[ll], cml(cb, iv));
      a1[ll] = cad(a1[ll], cml(cp, iv));
    }
  }
  cf* dst = A + (size_t)h * 4096 + l0;
  #pragma unroll
  for (int ll = 0; ll < 16; ll++){
    dst[ll] = cml(sC[ll], csb(a0[ll], cml(a1[ll], sWood[ll])));
  }
}

// ---------------- S0 table (circular pass): Sa/Sb from symmetrized A, bitrev-paired ----------------
__global__ __launch_bounds__(256) void k_s0(const cf* __restrict__ A, float4* __restrict__ S0){
  int hp = blockIdx.x;
  int rec = blockIdx.y * 256 + threadIdx.x;
  if (rec > 2048) return;
  int k = (rec < 2048) ? brev12(rec << 1) : 2048;
  int mk = (4096 - k) & 4095;
  const cf* a1p = A + (size_t)(2 * hp) * 4096;
  const cf* a2p = a1p + 4096;
  cf K1 = cad(a1p[k], cjg(a1p[mk]));   // 2*K1f[k]
  cf K2 = cad(a2p[k], cjg(a2p[mk]));
  const float s = 1.0f / 32768.0f;
  S0[(size_t)hp * 2049 + rec] = make_float4((K1.x + K2.x) * s, (K1.y + K2.y) * s,
                                            (K1.x - K2.x) * s, (K1.y - K2.y) * s);
}

// ---------------- T table (negacyclic): IDFT via dif(+1), gather, twist, dif(-1) ----------------
__global__ __launch_bounds__(1024) void k_kf(const cf* __restrict__ A, float4* __restrict__ Tt){
  __shared__ cf cb[4160];
  int hp = blockIdx.x, t = threadIdx.x;
  const cf* a1p = A + (size_t)(2 * hp) * 4096;
  const cf* a2p = a1p + 4096;
  cf v[4];
  #pragma unroll
  for (int r = 0; r < 4; r++){
    int n = t + 1024 * r;
    cf u = a1p[n], w = a2p[n];
    v[r] = cmk(u.x - w.y, u.y + w.x);          // A1 + i*A2, natural order
  }
  dif4096_reg4(v, cb, t, 1.0f);                // unscaled IDFT, scrambled in LDS
  const float inv = 1.0f / 4096.0f;
  #pragma unroll
  for (int r = 0; r < 4; r++){
    int n = t + 1024 * r;
    cf kv = cb[pidx(brev12(n))];               // k~[n] (unscaled)
    cf tw = twid((float)n * inv, -1.0f);       // tau[n]
    tw.x *= inv; tw.y *= inv;
    v[r] = cml(kv, tw);
  }
  dif4096_reg4(v, cb, t, -1.0f);               // Z = FFT(K~ * tau), scrambled
  float4* rec = Tt + (size_t)hp * 2048;
  const float st = 1.0f / 32768.0f;
  #pragma unroll
  for (int q = 0; q < 2; q++){
    int tr = t + 1024 * q;
    int p = tr << 1;
    int k = brev12(p);
    int qs = brev12(4095 - k);
    cf Zp = cb[pidx(p)], Zq = cb[pidx(qs)];
    float G1x = Zp.x + Zq.x, G1y = Zp.y - Zq.y;
    float dx = Zp.x - Zq.x, dy = Zp.y + Zq.y;
    rec[tr] = make_float4((G1x + dy) * st, (G1y - dx) * st,
                          (G1x - dy) * st, (G1y + dx) * st);
  }
}

// ---------------- conv: circular+negacyclic, 1024 threads, 4 cf/thread, acc in LDS ----------------
__global__ __launch_bounds__(1024) void k_conv(const float* __restrict__ xT,
                                               const float4* __restrict__ S0,
                                               const float4* __restrict__ Tt,
                                               const float* __restrict__ Dp,
                                               ushort* __restrict__ y1h,
                                               ushort* __restrict__ y1l){
  __shared__ cf cb[4160];
  __shared__ cf accs[4096];
  int blk = blockIdx.x;
  int b = blk >> 7, hp = blk & 127;
  int t = threadIdx.x;
  const float* xs1 = xT + ((size_t)(b * 256 + 2 * hp)) * 4096;
  const float* xs2 = xs1 + 4096;
  cf v[4];
  #pragma unroll
  for (int r = 0; r < 4; r++){
    int n = t + 1024 * r;
    v[r] = cmk(xs1[n], xs2[n]);
  }
  // ---- pass 0: circular ----
  dif4096_reg4(v, cb, t, -1.0f);
  {
    const float4* rec0 = S0 + (size_t)hp * 2049;
    #pragma unroll
    for (int q = 0; q < 2; q++){
      int tr = t + 1024 * q;
      int p = tr << 1;
      int k = brev12(p);
      int q0 = brev12((4096 - k) & 4095);
      int pi = pidx(p), qi = pidx(q0);
      cf Zp = cb[pi], Zq = cb[qi];
      float4 r0 = rec0[tr];
      cf Sa = cmk(r0.x, r0.y), Sb = cmk(r0.z, r0.w);
      cb[pi] = cad(cml(Zp, Sa), cml(cjg(Zq), Sb));
      cb[qi] = cad(cml(Zq, cjg(Sa)), cml(cjg(Zp), cjg(Sb)));
    }
    if (t == 0){
      float4 e = rec0[2048];
      cf Z1 = cb[1];
      cb[1] = cad(cml(Z1, cmk(e.x, e.y)), cml(cjg(Z1), cmk(e.z, e.w)));
    }
  }
  __syncthreads();
  dit4096_reg4(v, cb, t, 1.0f);
  #pragma unroll
  for (int r = 0; r < 4; r++) accs[t + 1024 * r] = v[r];   // own slots, no barrier needed
  // ---- pass 1: negacyclic (reload x + pre-twist) ----
  #pragma unroll
  for (int r = 0; r < 4; r++){
    int n = t + 1024 * r;
    cf xv = cmk(xs1[n], xs2[n]);
    v[r] = cml(xv, twid((float)n * (1.0f / 4096.0f), -1.0f));
  }
  dif4096_reg4(v, cb, t, -1.0f);
  {
    const float4* rec1 = Tt + (size_t)hp * 2048;
    #pragma unroll
    for (int q = 0; q < 2; q++){
      int tr = t + 1024 * q;
      int p = tr << 1;
      int k = brev12(p);
      int q1 = brev12(4095 - k);
      int pi = pidx(p), qi = pidx(q1);
      cf Zp = cb[pi], Zq = cb[qi];
      float4 r0 = rec1[tr];
      cf Ta = cmk(r0.x, r0.y), Tb = cmk(r0.z, r0.w);
      cb[pi] = cad(cml(Zp, Ta), cml(cjg(Zq), Tb));
      cb[qi] = cad(cml(Zq, cjg(Ta)), cml(cjg(Zp), cjg(Tb)));
    }
  }
  __syncthreads();
  dit4096_reg4(v, cb, t, 1.0f);
  // ---- combine (post-twist pass1) + epilogue (reload x) ----
  float Dv = Dp[0];
  size_t base = ((size_t)(b * 256 + 2 * hp)) * 4096;
  #pragma unroll
  for (int r = 0; r < 4; r++){
    int n = t + 1024 * r;
    cf u = cml(v[r], twid((float)n * (1.0f / 4096.0f), 1.0f));  // conj(tau)
    cf a = accs[t + 1024 * r];
    float y1 = a.x + u.x;
    float y2 = a.y + u.y;
    float z1 = geluf(fmaf(Dv, xs1[n], y1));
    float z2 = geluf(fmaf(Dv, xs2[n], y2));
    ushort h0, l0, h1u, l1;
    bfsplit(z1, &h0, &l0);
    bfsplit(z2, &h1u, &l1);
    y1h[base + n] = h0;         y1l[base + n] = l0;
    y1h[base + 4096 + n] = h1u; y1l[base + 4096 + n] = l1;
  }
}

// ---------------- MFMA split-bf16 GEMM + gelu + skip + LayerNorm + max|y| ----------------
__global__ __launch_bounds__(256, 3) void k_gemm_ln(
    const ushort* __restrict__ y1h, const ushort* __restrict__ y1l,
    const ushort* __restrict__ Wh, const ushort* __restrict__ Wl,
    const float* __restrict__ bfc, const float* __restrict__ x,
    const float* __restrict__ lng, const float* __restrict__ lnb,
    float* __restrict__ yout, unsigned* __restrict__ ymax)
{
  __shared__ ushort sY[2][64 * 40];
  __shared__ float red1[64][4], red2[64][4];
  int tid = threadIdx.x;
  int l = tid & 63;
  int w = tid >> 6;
  int blk = blockIdx.x;
  int b = blk >> 6;
  int t0 = (blk & 63) * 64;
  int g = l >> 4, cc = l & 15;

  f32x4 acc[4][4];
  #pragma unroll
  for (int m = 0; m < 4; m++)
    #pragma unroll
    for (int n = 0; n < 4; n++)
      acc[m][n] = (f32x4){0.0f, 0.0f, 0.0f, 0.0f};

  int kk = tid >> 3, ts = (tid & 7) * 8;

  #pragma unroll 1
  for (int kc = 0; kc < 256; kc += 32){
    __syncthreads();
    {
      size_t gb = ((size_t)(b * 256 + kc + kk)) * 4096 + t0 + ts;
      float4 vh = *(const float4*)(y1h + gb);
      float4 vl = *(const float4*)(y1l + gb);
      const ushort* ph = (const ushort*)&vh;
      const ushort* pl = (const ushort*)&vl;
      int kblk = kk >> 3, kin = kk & 7;
      #pragma unroll
      for (int e = 0; e < 8; e++){
        int t = ts + e;
        int idx = t * 40 + ((kblk ^ ((t >> 3) & 3)) << 3) + kin;
        sY[0][idx] = ph[e];
        sY[1][idx] = pl[e];
      }
    }
    __syncthreads();
    bf16x8 afh[4], afl[4];
    #pragma unroll
    for (int m = 0; m < 4; m++){
      int t = m * 16 + cc;
      int idx = t * 40 + ((g ^ ((t >> 3) & 3)) << 3);
      afh[m] = *(bf16x8*)&sY[0][idx];
      afl[m] = *(bf16x8*)&sY[1][idx];
    }
    #pragma unroll
    for (int n = 0; n < 4; n++){
      size_t wj = (size_t)(w * 64 + n * 16 + cc) * 256 + kc + g * 8;
      bf16x8 bh = *(const bf16x8*)(Wh + wj);
      bf16x8 bl = *(const bf16x8*)(Wl + wj);
      #pragma unroll
      for (int m = 0; m < 4; m++){
        acc[m][n] = __builtin_amdgcn_mfma_f32_16x16x32_bf16(afh[m], bh, acc[m][n], 0, 0, 0);
        acc[m][n] = __builtin_amdgcn_mfma_f32_16x16x32_bf16(afh[m], bl, acc[m][n], 0, 0, 0);
        acc[m][n] = __builtin_amdgcn_mfma_f32_16x16x32_bf16(afl[m], bh, acc[m][n], 0, 0, 0);
      }
    }
  }

  float bj[4], gj[4], lj[4];
  #pragma unroll
  for (int n = 0; n < 4; n++){
    int j = w * 64 + n * 16 + cc;
    bj[n] = bfc[j]; gj[n] = lng[j]; lj[n] = lnb[j];
  }
  #pragma unroll
  for (int m = 0; m < 4; m++){
    #pragma unroll
    for (int r = 0; r < 4; r++){
      int tl = m * 16 + g * 4 + r;
      size_t rowb = ((size_t)(b * 4096 + t0 + tl)) * 256;
      float ss = 0.0f, sq = 0.0f;
      #pragma unroll
      for (int n = 0; n < 4; n++){
        float z = geluf(acc[m][n][r] + bj[n]) + x[rowb + w * 64 + n * 16 + cc];
        acc[m][n][r] = z;
        ss += z; sq = fmaf(z, z, sq);
      }
      #pragma unroll
      for (int msk = 1; msk < 16; msk <<= 1){
        ss += __shfl_xor(ss, msk);
        sq += __shfl_xor(sq, msk);
      }
      if (cc == 0){ red1[tl][w] = ss; red2[tl][w] = sq; }
    }
  }
  __syncthreads();
  float jm[4] = {0.0f, 0.0f, 0.0f, 0.0f};
  #pragma unroll
  for (int m = 0; m < 4; m++){
    #pragma unroll
    for (int r = 0; r < 4; r++){
      int tl = m * 16 + g * 4 + r;
      float ts1 = red1[tl][0] + red1[tl][1] + red1[tl][2] + red1[tl][3];
      float ts2 = red2[tl][0] + red2[tl][1] + red2[tl][2] + red2[tl][3];
      float mu = ts1 * (1.0f / 256.0f);
      float var = ts2 * (1.0f / 256.0f) - mu * mu;
      float rstd = rsqrtf(var + 1e-5f);
      size_t rowb = ((size_t)(b * 4096 + t0 + tl)) * 256;
      #pragma unroll
      for (int n = 0; n < 4; n++){
        float yv = (acc[m][n][r] - mu) * rstd * gj[n] + lj[n];
        yout[rowb + w * 64 + n * 16 + cc] = yv;
        jm[n] = fmaxf(jm[n], fabsf(yv));
      }
    }
  }
  #pragma unroll
  for (int n = 0; n < 4; n++){
    jm[n] = fmaxf(jm[n], __shfl_xor(jm[n], 16));
    jm[n] = fmaxf(jm[n], __shfl_xor(jm[n], 32));
  }
  if (g == 0){
    #pragma unroll
    for (int n = 0; n < 4; n++)
      atomicMax(&ymax[b * 256 + w * 64 + n * 16 + cc], __float_as_uint(jm[n]));
  }
}

// ---------------- final ratio ----------------
__global__ void k_ratio(const unsigned* __restrict__ ymax, const unsigned* __restrict__ xmax,
                        float* __restrict__ out){
  int i = blockIdx.x * 256 + threadIdx.x;
  if (i < 2048){
    float ym = __uint_as_float(ymax[i]);
    float xm = __uint_as_float(xmax[i]);
    out[8388608 + i] = ym / (xm + 1e-6f);
  }
}

extern "C" void kernel_launch(void* const* d_in, const int* in_sizes, int n_in,
                              void* d_out, int out_size, void* d_ws, size_t ws_size,
                              hipStream_t stream)
{
  const float* x    = (const float*)d_in[0];
  const float* Lr   = (const float*)d_in[1];
  const float* Li   = (const float*)d_in[2];
  const float* Pr   = (const float*)d_in[3];
  const float* Pi   = (const float*)d_in[4];
  const float* Qr   = (const float*)d_in[5];
  const float* Qi   = (const float*)d_in[6];
  const float* Br   = (const float*)d_in[7];
  const float* Bi   = (const float*)d_in[8];
  const float* Cr   = (const float*)d_in[9];
  const float* Ci   = (const float*)d_in[10];
  const float* stp  = (const float*)d_in[11];
  const float* Dp   = (const float*)d_in[12];
  const float* Wfc  = (const float*)d_in[13];
  const float* bfc  = (const float*)d_in[14];
  const float* lng  = (const float*)d_in[15];
  const float* lnb  = (const float*)d_in[16];

  char* ws = (char*)d_ws;
  float*    xT   = (float*)(ws);                                     // 32 MB
  float4*   S0   = (float4*)(ws + ((size_t)32 << 20));               // ~4.0 MB
  float4*   Tt   = (float4*)(ws + ((size_t)36 << 20) + (512u << 10));// 4 MB
  cf*       A    = (cf*)(ws + ((size_t)41 << 20));                   // 8 MB (dead after k_kf/k_s0)
  ushort*   y1h  = (ushort*)(ws + ((size_t)41 << 20));               // 16 MB (overlays A)
  ushort*   y1l  = (ushort*)(ws + ((size_t)57 << 20));               // 16 MB
  ushort*   Wh   = (ushort*)(ws + ((size_t)73 << 20));               // 128 KB
  ushort*   Wl   = (ushort*)(ws + ((size_t)73 << 20) + (128u << 10));
  unsigned* xmax = (unsigned*)(ws + ((size_t)73 << 20) + (256u << 10));
  unsigned* ymax = xmax + 2048;

  k_init<<<8, 256, 0, stream>>>(xmax, ymax);
  dim3 gt(64, 4, 8);
  k_transpose_x<<<gt, 256, 0, stream>>>(x, xT, xmax);
  k_wsplit<<<256, 256, 0, stream>>>(Wfc, Wh, Wl);
  k_cauchy<<<256, 256, 0, stream>>>(Lr, Li, Pr, Pi, Qr, Qi, Br, Bi, Cr, Ci, stp, A);
  k_s0<<<dim3(128, 9), 256, 0, stream>>>(A, S0);
  k_kf<<<128, 1024, 0, stream>>>(A, Tt);
  k_conv<<<1024, 1024, 0, stream>>>(xT, S0, Tt, Dp, y1h, y1l);
  k_gemm_ln<<<512, 256, 0, stream>>>(y1h, y1l, Wh, Wl, bfc, x, lng, lnb, (float*)d_out, ymax);
  k_ratio<<<8, 256, 0, stream>>>(ymax, xmax, (float*)d_out);
}

// Round 9
// 213.814 us; speedup vs baseline: 1.7556x; 1.0057x over previous
//
#include <hip/hip_runtime.h>
#include <math.h>

typedef float2 cf;
typedef __attribute__((ext_vector_type(8))) short bf16x8;
typedef __attribute__((ext_vector_type(4))) float f32x4;

__device__ __forceinline__ cf cmk(float x, float y){ cf r; r.x=x; r.y=y; return r; }
__device__ __forceinline__ cf cml(cf a, cf b){ return cmk(a.x*b.x - a.y*b.y, a.x*b.y + a.y*b.x); }
__device__ __forceinline__ cf cad(cf a, cf b){ return cmk(a.x+b.x, a.y+b.y); }
__device__ __forceinline__ cf csb(cf a, cf b){ return cmk(a.x-b.x, a.y-b.y); }
__device__ __forceinline__ cf cjg(cf a){ return cmk(a.x, -a.y); }
__device__ __forceinline__ cf crcp(cf d){ float r = 1.0f/(d.x*d.x + d.y*d.y); return cmk(d.x*r, -d.y*r); }
__device__ __forceinline__ cf cdv(cf n, cf d){ return cml(n, crcp(d)); }
__device__ __forceinline__ float geluf(float z){ return 0.5f*z*(1.0f + erff(z*0.70710678118654752f)); }

// exp(sign*i*pi*f) via native v_sin/v_cos (input in revolutions)
__device__ __forceinline__ cf twid(float f, float sign){
  float h = f * 0.5f;
  float s = __builtin_amdgcn_sinf(h);
  float c0 = __builtin_amdgcn_cosf(h);
  return cmk(c0, sign * s);
}

__device__ __forceinline__ cf shflx(cf v, int m){
  return cmk(__shfl_xor(v.x, m), __shfl_xor(v.y, m));
}

__device__ __forceinline__ void bfsplit(float v, ushort* h, ushort* l){
  unsigned u = __float_as_uint(v);
  unsigned hr = (u + 0x7FFFu + ((u >> 16) & 1u)) & 0xFFFF0000u;
  *h = (ushort)(hr >> 16);
  float lv = v - __uint_as_float(hr);
  unsigned u2 = __float_as_uint(lv);
  *l = (ushort)((u2 + 0x7FFFu + ((u2 >> 16) & 1u)) >> 16);
}

// radix-4 butterflies on a register quad (element strides 0,S,2S,3S), w1 = twid(j/(2S))
__device__ __forceinline__ void dif4q(cf& q0, cf& q1, cf& q2, cf& q3, cf w1, float sign){
  cf w2 = cml(w1, w1);
  cf a1 = cad(q0, q2);
  cf c1 = cml(csb(q0, q2), w1);
  cf b1 = cad(q1, q3);
  cf d1 = cml(csb(q1, q3), cmk(-sign*w1.y, sign*w1.x));
  q0 = cad(a1, b1);
  q1 = cml(csb(a1, b1), w2);
  q2 = cad(c1, d1);
  q3 = cml(csb(c1, d1), w2);
}
__device__ __forceinline__ void dit4q(cf& q0, cf& q1, cf& q2, cf& q3, cf w1, float sign){
  cf w2 = cml(w1, w1);
  cf t1 = cml(q1, w2);
  cf a1 = cad(q0, t1), b1 = csb(q0, t1);
  cf t2 = cml(q3, w2);
  cf c1 = cad(q2, t2), d1 = csb(q2, t2);
  cf v1 = cml(c1, w1);
  cf v2 = cml(d1, cmk(-sign*w1.y, sign*w1.x));
  q0 = cad(a1, v1);
  q2 = csb(a1, v1);
  q1 = cad(b1, v2);
  q3 = csb(b1, v2);
}

__device__ __forceinline__ int brev12(int x){ return (int)(__brev((unsigned)x) >> 20); }
__device__ __forceinline__ int brev13(int x){ return (int)(__brev((unsigned)x) >> 19); }
__device__ __forceinline__ int pidx(int n){ return n + 4*(n>>8); }

// ---------------- legacy LDS FFT templates (k_kf only), TP-parameterized ----------------
template<int N, int SSTART, int TP>
__device__ void fft_dif_r4(cf* __restrict__ a, float sign){
  #pragma unroll
  for (int s = SSTART; s >= 1; s >>= 2){
    __syncthreads();
    #pragma unroll
    for (int g = 0; g < (N >> 2) / TP; g++){
      int w = (int)threadIdx.x + g * TP;
      int j = w & (s - 1);
      int base = ((w & ~(s - 1)) << 2) | j;
      cf A0 = a[base], B0 = a[base + s], C0 = a[base + 2*s], D0 = a[base + 3*s];
      cf w1 = twid((float)j / (float)(2 * s), sign);
      cf w2 = cml(w1, w1);
      cf a1 = cad(A0, C0);
      cf c1 = cml(csb(A0, C0), w1);
      cf b1 = cad(B0, D0);
      cf d1 = cml(csb(B0, D0), cmk(-sign * w1.y, sign * w1.x));
      a[base]         = cad(a1, b1);
      a[base + s]     = cml(csb(a1, b1), w2);
      a[base + 2*s]   = cad(c1, d1);
      a[base + 3*s]   = cml(csb(c1, d1), w2);
    }
  }
  if constexpr ((__builtin_ctz(N) & 1) == 1){
    __syncthreads();
    #pragma unroll
    for (int g = 0; g < (N >> 1) / TP; g++){
      int w = (int)threadIdx.x + g * TP;
      int i = w << 1;
      cf u = a[i], v = a[i + 1];
      a[i] = cad(u, v);
      a[i + 1] = csb(u, v);
    }
  }
  __syncthreads();
}

template<int N, int TP>
__device__ void fft_dit_r4(cf* __restrict__ a, float sign){
  if constexpr ((__builtin_ctz(N) & 1) == 1){
    __syncthreads();
    #pragma unroll
    for (int g = 0; g < (N >> 1) / TP; g++){
      int w = (int)threadIdx.x + g * TP;
      int i = w << 1;
      cf u = a[i], v = a[i + 1];
      a[i] = cad(u, v);
      a[i + 1] = csb(u, v);
    }
  }
  constexpr int S0 = ((__builtin_ctz(N) & 1) == 1) ? 2 : 1;
  #pragma unroll
  for (int s = S0; s <= (N >> 2); s <<= 2){
    __syncthreads();
    #pragma unroll
    for (int g = 0; g < (N >> 2) / TP; g++){
      int w = (int)threadIdx.x + g * TP;
      int j = w & (s - 1);
      int base = ((w & ~(s - 1)) << 2) | j;
      cf A0 = a[base], B0 = a[base + s], C0 = a[base + 2*s], D0 = a[base + 3*s];
      cf w1 = twid((float)j / (float)(2 * s), sign);
      cf w2 = cml(w1, w1);
      cf t1 = cml(B0, w2);
      cf a1 = cad(A0, t1), b1 = csb(A0, t1);
      cf t2 = cml(D0, w2);
      cf c1 = cad(C0, t2), d1 = csb(C0, t2);
      cf v1 = cml(c1, w1);
      cf v2 = cml(d1, cmk(-sign * w1.y, sign * w1.x));
      a[base]         = cad(a1, v1);
      a[base + 2*s]   = csb(a1, v1);
      a[base + s]     = cad(b1, v2);
      a[base + 3*s]   = csb(b1, v2);
    }
  }
  __syncthreads();
}

template<int TP>
__device__ void dif8192_pad_stage(cf* __restrict__ a, float sign){
  __syncthreads();
  #pragma unroll
  for (int g = 0; g < 2048 / TP; g++){
    int w = (int)threadIdx.x + g * TP;
    cf A0 = a[w], B0 = a[w + 2048];
    cf w1 = twid((float)w * (1.0f / 4096.0f), sign);
    cf w2 = cml(w1, w1);
    cf c1 = cml(A0, w1);
    cf d1 = cml(B0, cmk(-sign * w1.y, sign * w1.x));
    a[w]        = cad(A0, B0);
    a[w + 2048] = cml(csb(A0, B0), w2);
    a[w + 4096] = cad(c1, d1);
    a[w + 6144] = cml(csb(c1, d1), w2);
  }
}

// ---------------- init atomic-max buffers ----------------
__global__ void k_init(unsigned* xmax, unsigned* ymax){
  int i = blockIdx.x * 256 + threadIdx.x;
  if (i < 2048){ xmax[i] = 0u; ymax[i] = 0u; }
}

// ---------------- transpose x (B,L,H)->(B,H,L), fused max|x| ----------------
__global__ __launch_bounds__(256) void k_transpose_x(const float* __restrict__ x,
                                                     float* __restrict__ xT,
                                                     unsigned* __restrict__ xmax){
  __shared__ float tile[64][65];
  __shared__ float red[64][4];
  int b = blockIdx.z;
  int t0 = blockIdx.x * 64;
  int h0 = blockIdx.y * 64;
  int hc = threadIdx.x & 63, tg = threadIdx.x >> 6;
  float pmax = 0.0f;
  #pragma unroll
  for (int q = 0; q < 16; q++){
    int tr = tg + q * 4;
    float v = x[((size_t)(b * 4096 + t0 + tr)) * 256 + h0 + hc];
    tile[tr][hc] = v;
    pmax = fmaxf(pmax, fabsf(v));
  }
  red[hc][tg] = pmax;
  __syncthreads();
  if (threadIdx.x < 64){
    float m = fmaxf(fmaxf(red[threadIdx.x][0], red[threadIdx.x][1]),
                    fmaxf(red[threadIdx.x][2], red[threadIdx.x][3]));
    atomicMax(&xmax[b * 256 + h0 + threadIdx.x], __float_as_uint(m));
  }
  #pragma unroll
  for (int q = 0; q < 16; q++){
    int hr = tg + q * 4;
    xT[((size_t)(b * 256 + h0 + hr)) * 4096 + t0 + hc] = tile[hc][hr];
  }
}

// ---------------- W -> bf16 hi/lo planes ----------------
__global__ void k_wsplit(const float* __restrict__ W, ushort* __restrict__ Wh, ushort* __restrict__ Wl){
  int i = blockIdx.x * 256 + threadIdx.x;
  ushort h, l;
  bfsplit(W[i], &h, &l);
  Wh[i] = h; Wl[i] = l;
}

// ---------------- Cauchy / generating function ----------------
__global__ __launch_bounds__(256) void k_cauchy(
    const float* __restrict__ Lr, const float* __restrict__ Li,
    const float* __restrict__ Pr, const float* __restrict__ Pi,
    const float* __restrict__ Qr, const float* __restrict__ Qi,
    const float* __restrict__ Br, const float* __restrict__ Bi,
    const float* __restrict__ Cr, const float* __restrict__ Ci,
    const float* __restrict__ stepp, cf* __restrict__ A)
{
  __shared__ cf sLam[64], sB[64], sP[64], sQB[64], sQP[64];
  __shared__ cf sInv[64][16];
  __shared__ cf sWood[16], sC[16], sG[16];
  int tid = threadIdx.x;
  int l0 = blockIdx.x * 16;
  float stepv = fmaxf(stepp[0], 1e-6f);
  if (tid < 64){
    cf lam = cmk(Lr[tid], Li[tid]);
    cf b = cmk(Br[tid], Bi[tid]);
    cf p = cmk(Pr[tid], Pi[tid]);
    cf q = cmk(Qr[tid], Qi[tid]);
    sLam[tid] = lam; sB[tid] = b; sP[tid] = p;
    sQB[tid] = cml(q, b);
    sQP[tid] = cml(q, p);
  }
  __syncthreads();
  if (tid < 16){
    int l = l0 + tid;
    float ang = -6.2831855f * ((float)l * (1.0f / 4096.0f));
    cf Om = cmk(cosf(ang), sinf(ang));
    cf den = cmk(1.0f + Om.x, Om.y);
    cf num = cmk(1.0f - Om.x, -Om.y);
    cf rden = crcp(den);
    sC[tid] = cml(cmk(2.0f, 0.0f), rden);
    cf g = cml(num, rden);
    float sc = 2.0f / stepv;
    sG[tid] = cmk(g.x * sc, g.y * sc);
  }
  __syncthreads();
  for (int it = tid; it < 1024; it += 256){
    int n = it >> 4, ll = it & 15;
    sInv[n][ll] = crcp(csb(sG[ll], sLam[n]));
  }
  __syncthreads();
  if (tid < 16){
    cf k10 = cmk(0,0), k11 = cmk(0,0);
    for (int n = 0; n < 64; n++){
      k10 = cad(k10, cml(sQB[n], sInv[n][tid]));
      k11 = cad(k11, cml(sQP[n], sInv[n][tid]));
    }
    sWood[tid] = cdv(k10, cmk(1.0f + k11.x, k11.y));
  }
  __syncthreads();
  int h = tid;
  cf a0[16], a1[16];
  #pragma unroll
  for (int ll = 0; ll < 16; ll++){ a0[ll] = cmk(0,0); a1[ll] = cmk(0,0); }
  for (int n = 0; n < 64; n++){
    cf cc = cmk(Cr[h * 64 + n], Ci[h * 64 + n]);
    cf cb = cml(cc, sB[n]);
    cf cp = cml(cc, sP[n]);
    #pragma unroll
    for (int ll = 0; ll < 16; ll++){
      cf iv = sInv[n][ll];
      a0[ll] = cad(a0[ll], cml(cb, iv));
      a1[ll] = cad(a1[ll], cml(cp, iv));
    }
  }
  cf* dst = A + (size_t)h * 4096 + l0;
  #pragma unroll
  for (int ll = 0; ll < 16; ll++){
    dst[ll] = cml(sC[ll], csb(a0[ll], cml(a1[ll], sWood[ll])));
  }
}

// ---------------- Kf pair tables (Sab): ifft4096 -> pack -> fft8192, 512 threads ----------------
__global__ __launch_bounds__(512) void k_kf(const cf* __restrict__ A, float4* __restrict__ Sab){
  extern __shared__ cf c[];   // 8192 cf
  int hp = blockIdx.x, tid = threadIdx.x;
  const cf* a1p = A + (size_t)(2 * hp) * 4096;
  const cf* a2p = a1p + 4096;
  for (int l = tid; l < 4096; l += 512){
    int r = brev12(l);
    cf u = a1p[l], w = a2p[l];
    c[r] = cmk(u.x - w.y, u.y + w.x);          // A1 + i*A2, bitrev order
  }
  fft_dit_r4<4096, 512>(c, 1.0f);              // unscaled ifft -> k1 + i*k2, natural
  float k1[8], k2[8];
  #pragma unroll
  for (int q = 0; q < 8; q++){
    cf w = c[tid + q * 512];
    k1[q] = w.x * (1.0f / 4096.0f);
    k2[q] = w.y * (1.0f / 4096.0f);
  }
  __syncthreads();
  #pragma unroll
  for (int q = 0; q < 8; q++) c[tid + q * 512] = cmk(k1[q], k2[q]);  // upper half via pad stage
  dif8192_pad_stage<512>(c, -1.0f);
  fft_dif_r4<8192, 512, 512>(c, -1.0f);        // Z = K1f + i*K2f, brev13 order
  float4* rec = Sab + (size_t)hp * 4097;
  const float sc = 0.5f * 0.5f * (1.0f / 8192.0f);
  #pragma unroll
  for (int q8 = 0; q8 < 8; q8++){
    int t = tid + 512 * q8;
    int p = t << 1;
    int k = brev13(p);
    int qq = brev13((8192 - k) & 8191);
    cf Zp = c[p], Zq = c[qq];
    float K1x = (Zp.x + Zq.x), K1y = (Zp.y - Zq.y);
    float dx  = (Zp.x - Zq.x), dy  = (Zp.y + Zq.y);
    float K2x = dy, K2y = -dx;
    rec[t] = make_float4((K1x + K2x) * sc, (K1y + K2y) * sc,
                         (K1x - K2x) * sc, (K1y - K2y) * sc);
  }
  if (tid == 0){
    cf Z1 = c[1];
    float K1x = 2.0f * Z1.x, K2x = 2.0f * Z1.y;
    rec[4096] = make_float4((K1x + K2x) * sc, 0.0f, (K1x - K2x) * sc, 0.0f);
  }
}

// ---------------- conv: single 8192 FFT, 512 threads x 16 cf, 2 channels/block ----------------
// M0: n = t + 512r ; M1: n = a*512 + u*32 + c (a=t>>5, c=t&31). LDS slot = pidx(n). slot p <-> bin brev13(p).
__global__ __launch_bounds__(512) void k_conv(const float* __restrict__ xT,
                                              const float4* __restrict__ Sab,
                                              const float* __restrict__ Dp,
                                              ushort* __restrict__ y1h,
                                              ushort* __restrict__ y1l){
  __shared__ cf c[8320];
  int blk = blockIdx.x;
  int b = blk >> 7, hp = blk & 127;
  int t = threadIdx.x;
  int a = t >> 5, cl = t & 31;
  const float* xs1 = xT + ((size_t)(b * 256 + 2 * hp)) * 4096;
  const float* xs2 = xs1 + 4096;
  cf v[16];
  #pragma unroll
  for (int r = 0; r < 8; r++){
    int n = t + 512 * r;
    v[r] = cmk(xs1[n], xs2[n]);
  }
  // ---- forward (sign=-1) ----
  // bit 12 (zero-pad collapse)
  #pragma unroll
  for (int r = 0; r < 8; r++)
    v[r + 8] = cml(v[r], twid((float)(t + 512 * r) * (1.0f / 4096.0f), -1.0f));
  // bits 11,10
  #pragma unroll
  for (int h = 0; h < 16; h += 8){
    #pragma unroll
    for (int r0 = 0; r0 < 2; r0++){
      cf w1 = twid((float)(t + 512 * r0) * (1.0f / 2048.0f), -1.0f);
      dif4q(v[h + r0], v[h + r0 + 2], v[h + r0 + 4], v[h + r0 + 6], w1, -1.0f);
    }
  }
  // bit 9
  {
    cf tw = twid((float)t * (1.0f / 512.0f), -1.0f);
    #pragma unroll
    for (int r = 0; r < 16; r += 2){
      cf lo = cad(v[r], v[r + 1]);
      cf hi = cml(csb(v[r], v[r + 1]), tw);
      v[r] = lo; v[r + 1] = hi;
    }
  }
  // transpose M0 -> M1
  __syncthreads();
  #pragma unroll
  for (int r = 0; r < 16; r++) c[pidx(t + 512 * r)] = v[r];
  __syncthreads();
  #pragma unroll
  for (int u = 0; u < 16; u++) v[u] = c[pidx(a * 512 + u * 32 + cl)];
  // bits 8,7
  #pragma unroll
  for (int u0 = 0; u0 < 4; u0++){
    cf w1 = twid((float)(u0 * 32 + cl) * (1.0f / 256.0f), -1.0f);
    dif4q(v[u0], v[u0 + 4], v[u0 + 8], v[u0 + 12], w1, -1.0f);
  }
  // bits 6,5
  {
    cf w1 = twid((float)cl * (1.0f / 64.0f), -1.0f);
    #pragma unroll
    for (int g = 0; g < 16; g += 4)
      dif4q(v[g], v[g + 1], v[g + 2], v[g + 3], w1, -1.0f);
  }
  // bits 4..1 (shuffles with twiddle), bit 0 plain
  #pragma unroll
  for (int m = 16; m >= 2; m >>= 1){
    bool hb = (cl & m) != 0;
    cf tw = twid((float)(cl & (m - 1)) * (1.0f / (float)m), -1.0f);
    #pragma unroll
    for (int u = 0; u < 16; u++){
      cf o = shflx(v[u], m);
      v[u] = hb ? cml(csb(o, v[u]), tw) : cad(v[u], o);
    }
  }
  {
    bool hb = (cl & 1) != 0;
    #pragma unroll
    for (int u = 0; u < 16; u++){
      cf o = shflx(v[u], 1);
      v[u] = hb ? csb(o, v[u]) : cad(v[u], o);
    }
  }
  #pragma unroll
  for (int u = 0; u < 16; u++) c[pidx(a * 512 + u * 32 + cl)] = v[u];
  __syncthreads();
  // ---- pointwise (brev13 pairing) ----
  {
    const float4* rec = Sab + (size_t)hp * 4097;
    #pragma unroll
    for (int q8 = 0; q8 < 8; q8++){
      int th = t + 512 * q8;
      int p = th << 1;
      int k = brev13(p);
      int qq = brev13((8192 - k) & 8191);
      int pi = pidx(p), qi = pidx(qq);
      cf Zp = c[pi], Zq = c[qi];
      float4 r0 = rec[th];
      cf Sap = cmk(r0.x, r0.y), Sbp = cmk(r0.z, r0.w);
      c[pi] = cad(cml(Zp, Sap), cml(cjg(Zq), Sbp));
      c[qi] = cad(cml(Zq, cjg(Sap)), cml(cjg(Zp), cjg(Sbp)));
    }
    if (t == 0){
      float4 e = rec[4096];
      cf Z1 = c[pidx(1)];
      c[pidx(1)] = cad(cml(Z1, cmk(e.x, e.y)), cml(cjg(Z1), cmk(e.z, e.w)));
    }
  }
  __syncthreads();
  // ---- inverse (sign=+1) ----
  #pragma unroll
  for (int u = 0; u < 16; u++) v[u] = c[pidx(a * 512 + u * 32 + cl)];
  {
    bool hb = (cl & 1) != 0;
    #pragma unroll
    for (int u = 0; u < 16; u++){
      cf o = shflx(v[u], 1);
      v[u] = hb ? csb(o, v[u]) : cad(v[u], o);
    }
  }
  #pragma unroll
  for (int m = 2; m <= 16; m <<= 1){
    bool hb = (cl & m) != 0;
    cf w = twid((float)(cl & (m - 1)) * (1.0f / (float)m), 1.0f);
    #pragma unroll
    for (int u = 0; u < 16; u++){
      cf o = shflx(v[u], m);
      cf whv = cml(w, hb ? v[u] : o);
      v[u] = hb ? csb(o, whv) : cad(v[u], whv);
    }
  }
  // bits 5,6
  {
    cf w1 = twid((float)cl * (1.0f / 64.0f), 1.0f);
    #pragma unroll
    for (int g = 0; g < 16; g += 4)
      dit4q(v[g], v[g + 1], v[g + 2], v[g + 3], w1, 1.0f);
  }
  // bits 7,8
  #pragma unroll
  for (int u0 = 0; u0 < 4; u0++){
    cf w1 = twid((float)(u0 * 32 + cl) * (1.0f / 256.0f), 1.0f);
    dit4q(v[u0], v[u0 + 4], v[u0 + 8], v[u0 + 12], w1, 1.0f);
  }
  // transpose M1 -> M0
  #pragma unroll
  for (int u = 0; u < 16; u++) c[pidx(a * 512 + u * 32 + cl)] = v[u];
  __syncthreads();
  #pragma unroll
  for (int r = 0; r < 16; r++) v[r] = c[pidx(t + 512 * r)];
  // bit 9
  {
    cf tw = twid((float)t * (1.0f / 512.0f), 1.0f);
    #pragma unroll
    for (int r = 0; r < 16; r += 2){
      cf tb = cml(v[r + 1], tw);
      cf a0 = v[r];
      v[r] = cad(a0, tb);
      v[r + 1] = csb(a0, tb);
    }
  }
  // bits 10,11
  #pragma unroll
  for (int h = 0; h < 16; h += 8){
    #pragma unroll
    for (int r0 = 0; r0 < 2; r0++){
      cf w1 = twid((float)(t + 512 * r0) * (1.0f / 2048.0f), 1.0f);
      dit4q(v[h + r0], v[h + r0 + 2], v[h + r0 + 4], v[h + r0 + 6], w1, 1.0f);
    }
  }
  // bit 12 (only lower outputs needed) + epilogue
  float Dv = Dp[0];
  size_t base = ((size_t)(b * 256 + 2 * hp)) * 4096;
  #pragma unroll
  for (int r = 0; r < 8; r++){
    int n = t + 512 * r;
    cf w = cad(v[r], cml(v[r + 8], twid((float)n * (1.0f / 4096.0f), 1.0f)));
    float z1 = geluf(fmaf(Dv, xs1[n], w.x));
    float z2 = geluf(fmaf(Dv, xs2[n], w.y));
    ushort h0, l0, h1u, l1;
    bfsplit(z1, &h0, &l0);
    bfsplit(z2, &h1u, &l1);
    y1h[base + n] = h0;         y1l[base + n] = l0;
    y1h[base + 4096 + n] = h1u; y1l[base + 4096 + n] = l1;
  }
}

// ---------------- MFMA split-bf16 GEMM + gelu + skip + LayerNorm + max|y| ----------------
__global__ __launch_bounds__(256, 3) void k_gemm_ln(
    const ushort* __restrict__ y1h, const ushort* __restrict__ y1l,
    const ushort* __restrict__ Wh, const ushort* __restrict__ Wl,
    const float* __restrict__ bfc, const float* __restrict__ x,
    const float* __restrict__ lng, const float* __restrict__ lnb,
    float* __restrict__ yout, unsigned* __restrict__ ymax)
{
  __shared__ ushort sY[2][64 * 40];
  __shared__ float red1[64][4], red2[64][4];
  int tid = threadIdx.x;
  int l = tid & 63;
  int w = tid >> 6;
  int blk = blockIdx.x;
  int b = blk >> 6;
  int t0 = (blk & 63) * 64;
  int g = l >> 4, cc = l & 15;

  f32x4 acc[4][4];
  #pragma unroll
  for (int m = 0; m < 4; m++)
    #pragma unroll
    for (int n = 0; n < 4; n++)
      acc[m][n] = (f32x4){0.0f, 0.0f, 0.0f, 0.0f};

  int kk = tid >> 3, ts = (tid & 7) * 8;

  #pragma unroll 1
  for (int kc = 0; kc < 256; kc += 32){
    __syncthreads();
    {
      size_t gb = ((size_t)(b * 256 + kc + kk)) * 4096 + t0 + ts;
      float4 vh = *(const float4*)(y1h + gb);
      float4 vl = *(const float4*)(y1l + gb);
      const ushort* ph = (const ushort*)&vh;
      const ushort* pl = (const ushort*)&vl;
      int kblk = kk >> 3, kin = kk & 7;
      #pragma unroll
      for (int e = 0; e < 8; e++){
        int t = ts + e;
        int idx = t * 40 + ((kblk ^ ((t >> 3) & 3)) << 3) + kin;
        sY[0][idx] = ph[e];
        sY[1][idx] = pl[e];
      }
    }
    __syncthreads();
    bf16x8 afh[4], afl[4];
    #pragma unroll
    for (int m = 0; m < 4; m++){
      int t = m * 16 + cc;
      int idx = t * 40 + ((g ^ ((t >> 3) & 3)) << 3);
      afh[m] = *(bf16x8*)&sY[0][idx];
      afl[m] = *(bf16x8*)&sY[1][idx];
    }
    #pragma unroll
    for (int n = 0; n < 4; n++){
      size_t wj = (size_t)(w * 64 + n * 16 + cc) * 256 + kc + g * 8;
      bf16x8 bh = *(const bf16x8*)(Wh + wj);
      bf16x8 bl = *(const bf16x8*)(Wl + wj);
      #pragma unroll
      for (int m = 0; m < 4; m++){
        acc[m][n] = __builtin_amdgcn_mfma_f32_16x16x32_bf16(afh[m], bh, acc[m][n], 0, 0, 0);
        acc[m][n] = __builtin_amdgcn_mfma_f32_16x16x32_bf16(afh[m], bl, acc[m][n], 0, 0, 0);
        acc[m][n] = __builtin_amdgcn_mfma_f32_16x16x32_bf16(afl[m], bh, acc[m][n], 0, 0, 0);
      }
    }
  }

  float bj[4], gj[4], lj[4];
  #pragma unroll
  for (int n = 0; n < 4; n++){
    int j = w * 64 + n * 16 + cc;
    bj[n] = bfc[j]; gj[n] = lng[j]; lj[n] = lnb[j];
  }
  #pragma unroll
  for (int m = 0; m < 4; m++){
    #pragma unroll
    for (int r = 0; r < 4; r++){
      int tl = m * 16 + g * 4 + r;
      size_t rowb = ((size_t)(b * 4096 + t0 + tl)) * 256;
      float ss = 0.0f, sq = 0.0f;
      #pragma unroll
      for (int n = 0; n < 4; n++){
        float z = geluf(acc[m][n][r] + bj[n]) + x[rowb + w * 64 + n * 16 + cc];
        acc[m][n][r] = z;
        ss += z; sq = fmaf(z, z, sq);
      }
      #pragma unroll
      for (int msk = 1; msk < 16; msk <<= 1){
        ss += __shfl_xor(ss, msk);
        sq += __shfl_xor(sq, msk);
      }
      if (cc == 0){ red1[tl][w] = ss; red2[tl][w] = sq; }
    }
  }
  __syncthreads();
  float jm[4] = {0.0f, 0.0f, 0.0f, 0.0f};
  #pragma unroll
  for (int m = 0; m < 4; m++){
    #pragma unroll
    for (int r = 0; r < 4; r++){
      int tl = m * 16 + g * 4 + r;
      float ts1 = red1[tl][0] + red1[tl][1] + red1[tl][2] + red1[tl][3];
      float ts2 = red2[tl][0] + red2[tl][1] + red2[tl][2] + red2[tl][3];
      float mu = ts1 * (1.0f / 256.0f);
      float var = ts2 * (1.0f / 256.0f) - mu * mu;
      float rstd = rsqrtf(var + 1e-5f);
      size_t rowb = ((size_t)(b * 4096 + t0 + tl)) * 256;
      #pragma unroll
      for (int n = 0; n < 4; n++){
        float yv = (acc[m][n][r] - mu) * rstd * gj[n] + lj[n];
        yout[rowb + w * 64 + n * 16 + cc] = yv;
        jm[n] = fmaxf(jm[n], fabsf(yv));
      }
    }
  }
  #pragma unroll
  for (int n = 0; n < 4; n++){
    jm[n] = fmaxf(jm[n], __shfl_xor(jm[n], 16));
    jm[n] = fmaxf(jm[n], __shfl_xor(jm[n], 32));
  }
  if (g == 0){
    #pragma unroll
    for (int n = 0; n < 4; n++)
      atomicMax(&ymax[b * 256 + w * 64 + n * 16 + cc], __float_as_uint(jm[n]));
  }
}

// ---------------- final ratio ----------------
__global__ void k_ratio(const unsigned* __restrict__ ymax, const unsigned* __restrict__ xmax,
                        float* __restrict__ out){
  int i = blockIdx.x * 256 + threadIdx.x;
  if (i < 2048){
    float ym = __uint_as_float(ymax[i]);
    float xm = __uint_as_float(xmax[i]);
    out[8388608 + i] = ym / (xm + 1e-6f);
  }
}

extern "C" void kernel_launch(void* const* d_in, const int* in_sizes, int n_in,
                              void* d_out, int out_size, void* d_ws, size_t ws_size,
                              hipStream_t stream)
{
  const float* x    = (const float*)d_in[0];
  const float* Lr   = (const float*)d_in[1];
  const float* Li   = (const float*)d_in[2];
  const float* Pr   = (const float*)d_in[3];
  const float* Pi   = (const float*)d_in[4];
  const float* Qr   = (const float*)d_in[5];
  const float* Qi   = (const float*)d_in[6];
  const float* Br   = (const float*)d_in[7];
  const float* Bi   = (const float*)d_in[8];
  const float* Cr   = (const float*)d_in[9];
  const float* Ci   = (const float*)d_in[10];
  const float* stp  = (const float*)d_in[11];
  const float* Dp   = (const float*)d_in[12];
  const float* Wfc  = (const float*)d_in[13];
  const float* bfc  = (const float*)d_in[14];
  const float* lng  = (const float*)d_in[15];
  const float* lnb  = (const float*)d_in[16];

  char* ws = (char*)d_ws;
  float*    xT   = (float*)(ws);                                     // 32 MB
  float4*   Sab  = (float4*)(ws + ((size_t)32 << 20));               // ~8.4 MB (128*4097*16)
  cf*       A    = (cf*)(ws + ((size_t)41 << 20));                   // 8 MB (dead after k_kf)
  ushort*   y1h  = (ushort*)(ws + ((size_t)41 << 20));               // 16 MB (overlays A)
  ushort*   y1l  = (ushort*)(ws + ((size_t)57 << 20));               // 16 MB
  ushort*   Wh   = (ushort*)(ws + ((size_t)73 << 20));               // 128 KB
  ushort*   Wl   = (ushort*)(ws + ((size_t)73 << 20) + (128u << 10));
  unsigned* xmax = (unsigned*)(ws + ((size_t)73 << 20) + (256u << 10));
  unsigned* ymax = xmax + 2048;

  k_init<<<8, 256, 0, stream>>>(xmax, ymax);
  dim3 gt(64, 4, 8);
  k_transpose_x<<<gt, 256, 0, stream>>>(x, xT, xmax);
  k_wsplit<<<256, 256, 0, stream>>>(Wfc, Wh, Wl);
  k_cauchy<<<256, 256, 0, stream>>>(Lr, Li, Pr, Pi, Qr, Qi, Br, Bi, Cr, Ci, stp, A);
  k_kf<<<128, 512, 65536, stream>>>(A, Sab);
  k_conv<<<1024, 512, 0, stream>>>(xT, Sab, Dp, y1h, y1l);
  k_gemm_ln<<<512, 256, 0, stream>>>(y1h, y1l, Wh, Wl, bfc, x, lng, lnb, (float*)d_out, ymax);
  k_ratio<<<8, 256, 0, stream>>>(ymax, xmax, (float*)d_out);
}